// Round 8
// baseline (637.907 us; speedup 1.0000x reference)
//
#include <hip/hip_runtime.h>
#include <cstdint>
#include <cstddef>

typedef unsigned short u16;
typedef __attribute__((ext_vector_type(4))) float f32x4;
typedef __attribute__((ext_vector_type(8))) short bf16x8;
typedef __attribute__((ext_vector_type(8))) unsigned short u16x8;

// ---------- helpers ----------
__device__ __forceinline__ float sigm(float x) { return 1.f / (1.f + __expf(-x)); }
__device__ __forceinline__ float bf2f(u16 u) {
    union { unsigned int i; float f; } c; c.i = ((unsigned int)u) << 16; return c.f;
}
__device__ __forceinline__ u16 f2bf(float f) {
    union { float f; unsigned int i; } c; c.f = f;
    unsigned int x = c.i;
    x += 0x7fffu + ((x >> 16) & 1u);
    return (u16)(x >> 16);
}

// dims: D=512, H=8, DH=64, F=2048, K=31, L=512, N=16, M=8192

// ---------- fused weight cast fp32 -> bf16 (10 arrays incl. pos_w, pos_emb) ----------
__global__ void castall_k(const float* __restrict__ s0, const float* __restrict__ s1,
                          const float* __restrict__ s2, const float* __restrict__ s3,
                          const float* __restrict__ s4, const float* __restrict__ s5,
                          const float* __restrict__ s6, const float* __restrict__ s7,
                          const float* __restrict__ s8, const float* __restrict__ s9,
                          u16* __restrict__ dst) {
    int i = blockIdx.x * 256 + threadIdx.x;
    if (i >= 6815232) return;
    const float* s; int off;
    if      (i < 1048576) { s = s0; off = 0; }
    else if (i < 2097152) { s = s1; off = 1048576; }
    else if (i < 3145728) { s = s2; off = 2097152; }
    else if (i < 4194304) { s = s3; off = 3145728; }
    else if (i < 4980736) { s = s4; off = 4194304; }
    else if (i < 5242880) { s = s5; off = 4980736; }
    else if (i < 5767168) { s = s6; off = 5242880; }
    else if (i < 6029312) { s = s7; off = 5767168; }
    else if (i < 6291456) { s = s8; off = 6029312; }
    else                  { s = s9; off = 6291456; }
    dst[i] = f2bf(s[i - off]);
}

// ---------- LayerNorm over 512 (fp32 in), 4 rows per 256-thread block ----------
template <bool OUTBF>
__global__ __launch_bounds__(256) void ln512_k(const float* __restrict__ x,
                                               const float* __restrict__ g,
                                               const float* __restrict__ b,
                                               void* __restrict__ outv) {
    int row = blockIdx.x * 4 + (threadIdx.x >> 6);
    int lane = threadIdx.x & 63;
    const float* xr = x + (size_t)row * 512 + lane * 8;
    float4 v0 = *(const float4*)(xr);
    float4 v1 = *(const float4*)(xr + 4);
    float va[8] = {v0.x, v0.y, v0.z, v0.w, v1.x, v1.y, v1.z, v1.w};
    float s = 0.f;
#pragma unroll
    for (int t = 0; t < 8; t++) s += va[t];
#pragma unroll
    for (int o = 32; o > 0; o >>= 1) s += __shfl_xor(s, o);
    float m = s * (1.0f / 512.0f);
    float q = 0.f;
#pragma unroll
    for (int t = 0; t < 8; t++) { float d = va[t] - m; q += d * d; }
#pragma unroll
    for (int o = 32; o > 0; o >>= 1) q += __shfl_xor(q, o);
    float inv = rsqrtf(q * (1.0f / 512.0f) + 1e-5f);
    int cb = lane * 8;
    if (OUTBF) {
        u16* o = (u16*)outv + (size_t)row * 512 + cb;
#pragma unroll
        for (int t = 0; t < 8; t++)
            o[t] = f2bf((va[t] - m) * inv * g[cb + t] + b[cb + t]);
    } else {
        float* o = (float*)outv + (size_t)row * 512 + cb;
#pragma unroll
        for (int t = 0; t < 8; t++)
            o[t] = (va[t] - m) * inv * g[cb + t] + b[cb + t];
    }
}

// ---------- MFMA GEMM v6: wave-private split-K, NO K-loop barriers, 2:1 MFMA:ds_read ----------
// R7 theory: mgemm64's per-wave 32x32 quadrant = 1:1 MFMA:ds_read (8 FLOP/LDS-byte,
// 4x below the 32.8 FLOP/B LDS/MFMA balance point) + a vmcnt(0)-draining barrier
// every K-step. Fix: 128-thr blocks, 64x64 tile; each wave computes the FULL 64x64
// over HALF of K with its own private dbuf LDS (A+B, 32KB/block -> 5 blocks/CU,
// 10 waves/CU). Per wave K-step: 8 async stages + 8 ds_read : 16 MFMA (2:1, at
// balance). No __syncthreads in K-loop; per-wave s_waitcnt vmcnt(0) AFTER COMP so
// prefetch latency hides under ~170cy compute. Buffer-reuse safe: MFMA consumption
// forces lgkmcnt completion of prior ds_reads before next STAGE issues (program
// order). One barrier total (cross-wave K-reduction via the same LDS).
__global__ __launch_bounds__(128) void mgemmsk_k(
    const u16* __restrict__ A, const u16* __restrict__ B, const float* __restrict__ bias,
    const float* __restrict__ add, void* __restrict__ Cv,
    int M, int Nn, int Kk, float coef, int act, int outbf) {
    __shared__ u16 sh[16384];   // 32 KiB: wave w owns u16 [w*8192, +8192): A 2x2048, B 2x2048
    int tid = threadIdx.x;
    int lane = tid & 63, w = tid >> 6;       // w in {0,1}
    int quad = lane >> 4, rl = lane & 15;
    int m0 = blockIdx.x << 6, n0 = blockIdx.y << 6;
    int Kh = Kk >> 1;
    int kb = w * Kh;                          // this wave's K-origin

    f32x4 acc[4][4];
#pragma unroll
    for (int i = 0; i < 4; i++)
#pragma unroll
        for (int j = 0; j < 4; j++) acc[i][j] = (f32x4){0.f, 0.f, 0.f, 0.f};

    int srow = lane >> 2;                     // 0..15 (staging row within 16-row group)
    int scol = (lane & 3) << 3;               // 0,8,16,24 (k-offset u16)
    const u16* gAs = A + (size_t)(m0 + srow) * Kk + kb + scol;
    const u16* gBs = B + (size_t)(n0 + srow) * Kk + kb + scol;
    u16* myA = sh + (w << 13);                // w*8192
    u16* myB = myA + 4096;
    int lso = lane << 3;                      // lane*16B in u16

    auto STAGE = [&](int buf, int k0) {
#pragma unroll
        for (int i = 0; i < 4; i++) {
            __builtin_amdgcn_global_load_lds(
                (const __attribute__((address_space(1))) void*)(gAs + (size_t)(i * 16) * Kk + k0),
                (__attribute__((address_space(3))) void*)(myA + (buf << 11) + (i << 9) + lso), 16, 0, 0);
            __builtin_amdgcn_global_load_lds(
                (const __attribute__((address_space(1))) void*)(gBs + (size_t)(i * 16) * Kk + k0),
                (__attribute__((address_space(3))) void*)(myB + (buf << 11) + (i << 9) + lso), 16, 0, 0);
        }
    };
    auto COMP = [&](int buf) {
        bf16x8 af[4], bf[4];
#pragma unroll
        for (int t = 0; t < 4; t++) {
            af[t] = *(const bf16x8*)(myA + (buf << 11) + (t * 16 + rl) * 32 + quad * 8);
            bf[t] = *(const bf16x8*)(myB + (buf << 11) + (t * 16 + rl) * 32 + quad * 8);
        }
#pragma unroll
        for (int i = 0; i < 4; i++)
#pragma unroll
            for (int j = 0; j < 4; j++)
                acc[i][j] = __builtin_amdgcn_mfma_f32_16x16x32_bf16(af[i], bf[j], acc[i][j], 0, 0, 0);
    };

    int nk = Kh >> 5;
    STAGE(0, 0);
    asm volatile("s_waitcnt vmcnt(0)" ::: "memory");   // buf0 landed (this wave's 8 loads)
    for (int kt = 1; kt < nk; kt++) {
        STAGE(kt & 1, kt << 5);                        // prefetch next (8 loads in flight)
        COMP((kt - 1) & 1);                            // compute current (ready)
        asm volatile("s_waitcnt vmcnt(0)" ::: "memory"); // next landed; latency hidden by COMP
    }
    COMP((nk - 1) & 1);

    // ---- cross-wave K-reduction via LDS (reuse own staging region), then epilogue ----
    float* part = (float*)(sh) + (w << 12);   // w*4096 floats = own 16KB region
#pragma unroll
    for (int i = 0; i < 4; i++)
#pragma unroll
        for (int j = 0; j < 4; j++)
#pragma unroll
            for (int r = 0; r < 4; r++)
                part[(i * 16 + quad * 4 + r) * 64 + j * 16 + rl] = acc[i][j][r];
    __syncthreads();
    const float* p0 = (const float*)sh;
    const float* p1 = (const float*)sh + 4096;
    int cc = (lane & 15) << 2;                // col 0..60 step 4
    int r0 = (w << 5) + (lane >> 4);          // base row; + s*4
#pragma unroll
    for (int s = 0; s < 8; s++) {
        int lrow = r0 + (s << 2);
        f32x4 v0 = *(const f32x4*)(p0 + lrow * 64 + cc);
        f32x4 v1 = *(const f32x4*)(p1 + lrow * 64 + cc);
        int m = m0 + lrow;
        int n = n0 + cc;
#pragma unroll
        for (int r = 0; r < 4; r++) {
            float c = v0[r] + v1[r] + (bias ? bias[n + r] : 0.f);
            if (act == 1) c *= sigm(c);
            size_t o = (size_t)m * Nn + n + r;
            if (add) c = add[o] + coef * c;
            if (outbf) ((u16*)Cv)[o] = f2bf(c);
            else ((float*)Cv)[o] = c;
        }
    }
}

// ---------- pw1 GEMM with fused GLU epilogue: out(M,512) = a * sigm(gate) ----------
__global__ __launch_bounds__(256) void mgemmglu_k(
    const u16* __restrict__ A, const u16* __restrict__ B, const float* __restrict__ bias,
    u16* __restrict__ Cv, int Kk) {
    __shared__ u16 lA[2][2048];
    __shared__ u16 lBa[2][2048];
    __shared__ u16 lBg[2][2048];
    int tid = threadIdx.x;
    int lane = tid & 63;
    int w = tid >> 6;
    int quad = lane >> 4, rl = lane & 15;
    int wm = (w >> 1) * 32, wn = (w & 1) * 32;
    int m0 = blockIdx.x << 6, n0 = blockIdx.y << 6;

    f32x4 accA[2][2], accG[2][2];
#pragma unroll
    for (int i = 0; i < 2; i++)
#pragma unroll
        for (int j = 0; j < 2; j++) {
            accA[i][j] = (f32x4){0.f, 0.f, 0.f, 0.f};
            accG[i][j] = (f32x4){0.f, 0.f, 0.f, 0.f};
        }

    int srow = tid >> 2;
    int scol = (tid & 3) << 3;
    const u16* gA  = A + (size_t)(m0 + srow) * Kk + scol;
    const u16* gBa = B + (size_t)(n0 + srow) * Kk + scol;
    const u16* gBg = B + (size_t)(512 + n0 + srow) * Kk + scol;
    int lso = tid * 8;
    int lra = wm * 32 + rl * 32 + quad * 8;
    int lrb = wn * 32 + rl * 32 + quad * 8;

    auto STAGE = [&](int buf, int k0) {
        __builtin_amdgcn_global_load_lds(
            (const __attribute__((address_space(1))) void*)(gA + k0),
            (__attribute__((address_space(3))) void*)(lA[buf] + lso), 16, 0, 0);
        __builtin_amdgcn_global_load_lds(
            (const __attribute__((address_space(1))) void*)(gBa + k0),
            (__attribute__((address_space(3))) void*)(lBa[buf] + lso), 16, 0, 0);
        __builtin_amdgcn_global_load_lds(
            (const __attribute__((address_space(1))) void*)(gBg + k0),
            (__attribute__((address_space(3))) void*)(lBg[buf] + lso), 16, 0, 0);
    };
    auto COMP = [&](int buf) {
        bf16x8 af[2], ba[2], bg[2];
#pragma unroll
        for (int t = 0; t < 2; t++) {
            af[t] = *(const bf16x8*)(lA[buf] + lra + t * 512);
            ba[t] = *(const bf16x8*)(lBa[buf] + lrb + t * 512);
            bg[t] = *(const bf16x8*)(lBg[buf] + lrb + t * 512);
        }
#pragma unroll
        for (int i = 0; i < 2; i++)
#pragma unroll
            for (int j = 0; j < 2; j++) {
                accA[i][j] = __builtin_amdgcn_mfma_f32_16x16x32_bf16(af[i], ba[j], accA[i][j], 0, 0, 0);
                accG[i][j] = __builtin_amdgcn_mfma_f32_16x16x32_bf16(af[i], bg[j], accG[i][j], 0, 0, 0);
            }
    };

    int nk = Kk >> 5;
    STAGE(0, 0);
    __syncthreads();
    for (int kt = 1; kt < nk; kt++) {
        STAGE(kt & 1, kt << 5);
        COMP((kt - 1) & 1);
        __syncthreads();
    }
    COMP((nk - 1) & 1);

    int rbase = quad * 4;
#pragma unroll
    for (int i = 0; i < 2; i++) {
#pragma unroll
        for (int j = 0; j < 2; j++) {
            int n = n0 + wn + j * 16 + rl;
            float bva = bias[n], bvg = bias[512 + n];
#pragma unroll
            for (int r = 0; r < 4; r++) {
                int m = m0 + wm + i * 16 + rbase + r;
                float a = accA[i][j][r] + bva;
                float g = accG[i][j][r] + bvg;
                Cv[(size_t)m * 512 + n] = f2bf(a * sigm(g));
            }
        }
    }
}

// ---------- pos GEMM (bf16): Pbf[h][m][d] = pos_emb(1023x512) @ pos_w(512x512)^T ----------
__global__ __launch_bounds__(256) void posb_k(const u16* __restrict__ A,
                                              const u16* __restrict__ B,
                                              u16* __restrict__ Pbf) {
    __shared__ u16 lA[4096];
    __shared__ u16 lB[4096];
    const int Kk = 512;
    int tid = threadIdx.x;
    int lane = tid & 63, w = tid >> 6;
    int wm = (w >> 1) * 64, wn = (w & 1) * 64;
    int m0 = blockIdx.x << 7, n0 = blockIdx.y << 7;

    f32x4 acc[4][4];
#pragma unroll
    for (int i = 0; i < 4; i++)
#pragma unroll
        for (int j = 0; j < 4; j++) acc[i][j] = (f32x4){0.f, 0.f, 0.f, 0.f};

    int srow = tid >> 2;
    int scol = (tid & 3) << 3;
    int ar0 = m0 + srow;       if (ar0 > 1022) ar0 = 1022;
    int ar1 = m0 + 64 + srow;  if (ar1 > 1022) ar1 = 1022;
    const u16* gA0 = A + (size_t)ar0 * Kk + scol;
    const u16* gA1 = A + (size_t)ar1 * Kk + scol;
    const u16* gB = B + (size_t)(n0 + srow) * Kk + scol;
    int lso = tid * 8;
    int lra = wm * 32 + (lane & 15) * 32 + (lane >> 4) * 8;
    int lrb = wn * 32 + (lane & 15) * 32 + (lane >> 4) * 8;

    for (int k0 = 0; k0 < Kk; k0 += 32) {
        __builtin_amdgcn_global_load_lds(
            (const __attribute__((address_space(1))) void*)(gA0 + k0),
            (__attribute__((address_space(3))) void*)(lA + lso), 16, 0, 0);
        __builtin_amdgcn_global_load_lds(
            (const __attribute__((address_space(1))) void*)(gA1 + k0),
            (__attribute__((address_space(3))) void*)(lA + 2048 + lso), 16, 0, 0);
        __builtin_amdgcn_global_load_lds(
            (const __attribute__((address_space(1))) void*)(gB + k0),
            (__attribute__((address_space(3))) void*)(lB + lso), 16, 0, 0);
        __builtin_amdgcn_global_load_lds(
            (const __attribute__((address_space(1))) void*)(gB + (size_t)64 * Kk + k0),
            (__attribute__((address_space(3))) void*)(lB + 2048 + lso), 16, 0, 0);
        __syncthreads();
        bf16x8 af[4], bf[4];
#pragma unroll
        for (int t = 0; t < 4; t++) {
            af[t] = *(const bf16x8*)(lA + lra + t * 512);
            bf[t] = *(const bf16x8*)(lB + lrb + t * 512);
        }
#pragma unroll
        for (int i = 0; i < 4; i++)
#pragma unroll
            for (int j = 0; j < 4; j++)
                acc[i][j] = __builtin_amdgcn_mfma_f32_16x16x32_bf16(af[i], bf[j], acc[i][j], 0, 0, 0);
        __syncthreads();
    }

    int rbase = (lane >> 4) * 4;
    int ncol = lane & 15;
#pragma unroll
    for (int i = 0; i < 4; i++) {
#pragma unroll
        for (int j = 0; j < 4; j++) {
            int n = n0 + wn + j * 16 + ncol;
            int h = n >> 6, d = n & 63;
#pragma unroll
            for (int r = 0; r < 4; r++) {
                int m = m0 + wm + i * 16 + rbase + r;
                u16 val = (m < 1023) ? f2bf(acc[i][j][r]) : (u16)0;
                Pbf[(((size_t)(h * 1024 + m)) << 6) + d] = val;
            }
        }
    }
}

// ---------- fused flash attention v2 (best measured) ----------
__global__ __launch_bounds__(256) void fattn_k(
    const u16* __restrict__ QU, const u16* __restrict__ QV,
    const u16* __restrict__ Kb, const u16* __restrict__ Pbf,
    const u16* __restrict__ VT, u16* __restrict__ ctx) {
    __shared__ u16 arr[19072];            // 38,144 B -> 4 blocks/CU by LDS
    u16* sRect = arr;                     // bd shifted: 32 rows x stride 524 (scalar acc)
    u16* sP = arr;                        // alias: probs 32 x stride 520 (b128 reads)
    u16* sCtx = arr + 16768;              // 32 x 64 (disjoint from sP)
    float* sRed = (float*)(arr + 18816);  // 32 x 4 floats

    int tid = threadIdx.x;
    int lane = tid & 63, w = tid >> 6;
    int quad = lane >> 4, col = lane & 15;
    int nh = blockIdx.x, h = nh & 7, nb = nh >> 3;
    int m0 = blockIdx.y << 5;             // 32 q-rows per block
    int nlo = 480 - m0;                   // P window: rows nlo..nlo+543 (<=1023)

    const u16* QVz = QV + ((size_t)nh << 15);
    const u16* QUz = QU + ((size_t)nh << 15);
    const u16* Kz  = Kb + ((size_t)nh << 15);
    const u16* Vz  = VT + ((size_t)nh << 15);
    const u16* Pb  = Pbf + ((size_t)h << 16);

    // ---- phase 1: bd(32x544) = QV_tile . P^T, per-tile accumulators retired to sRect ----
    bf16x8 av[2][2];
#pragma unroll
    for (int ks = 0; ks < 2; ks++)
#pragma unroll
        for (int t = 0; t < 2; t++)
            av[ks][t] = *(const bf16x8*)(QVz + ((size_t)(m0 + t * 16 + col) << 6) + (ks << 5) + quad * 8);
#pragma unroll
    for (int idx = 0; idx < 9; idx++) {
        int nt = w + (idx << 2);
        if (nt < 34) {
            int crow = nt * 16 + col;
            const u16* pb = Pb + ((size_t)(nlo + crow) << 6) + quad * 8;
            f32x4 b0 = (f32x4){0.f, 0.f, 0.f, 0.f};
            f32x4 b1 = (f32x4){0.f, 0.f, 0.f, 0.f};
#pragma unroll
            for (int ks = 0; ks < 2; ks++) {
                bf16x8 bfr = *(const bf16x8*)(pb + (ks << 5));
                b0 = __builtin_amdgcn_mfma_f32_16x16x32_bf16(av[ks][0], bfr, b0, 0, 0, 0);
                b1 = __builtin_amdgcn_mfma_f32_16x16x32_bf16(av[ks][1], bfr, b1, 0, 0, 0);
            }
            // shifted write: rect col c -> j = c + ml - 31; stride 524
#pragma unroll
            for (int r = 0; r < 4; r++) {
                int ml0 = quad * 4 + r;
                int j0 = crow + ml0 - 31;
                if (j0 >= 0 && j0 < 512) sRect[ml0 * 524 + j0] = f2bf(b0[r]);
                int ml1 = ml0 + 16;
                int j1 = crow + ml1 - 31;
                if (j1 >= 0 && j1 < 512) sRect[ml1 * 524 + j1] = f2bf(b1[r]);
            }
        }
    }

    // ---- phase 2: ac(32x512) = QU_tile . K^T (direct reads, no barriers) ----
    bf16x8 au[2][2];
#pragma unroll
    for (int ks = 0; ks < 2; ks++)
#pragma unroll
        for (int t = 0; t < 2; t++)
            au[ks][t] = *(const bf16x8*)(QUz + ((size_t)(m0 + t * 16 + col) << 6) + (ks << 5) + quad * 8);
    f32x4 ac[2][8];
#pragma unroll
    for (int t = 0; t < 2; t++)
#pragma unroll
        for (int jt = 0; jt < 8; jt++) ac[t][jt] = (f32x4){0.f, 0.f, 0.f, 0.f};
#pragma unroll
    for (int jt = 0; jt < 8; jt++) {
        const u16* kp = Kz + ((size_t)((w << 7) + jt * 16 + col) << 6) + quad * 8;
#pragma unroll
        for (int ks = 0; ks < 2; ks++) {
            bf16x8 bfr = *(const bf16x8*)(kp + (ks << 5));
            ac[0][jt] = __builtin_amdgcn_mfma_f32_16x16x32_bf16(au[ks][0], bfr, ac[0][jt], 0, 0, 0);
            ac[1][jt] = __builtin_amdgcn_mfma_f32_16x16x32_bf16(au[ks][1], bfr, ac[1][jt], 0, 0, 0);
        }
    }
    __syncthreads();  // all sRect writes visible before phase-3 reads

    // ---- phase 3: shifted add + scale + softmax over j ----
    float rmax[2][4];
#pragma unroll
    for (int t = 0; t < 2; t++)
#pragma unroll
        for (int r = 0; r < 4; r++) rmax[t][r] = -1e30f;
#pragma unroll
    for (int jt = 0; jt < 8; jt++) {
        int j = (w << 7) + jt * 16 + col;
#pragma unroll
        for (int t = 0; t < 2; t++)
#pragma unroll
            for (int r = 0; r < 4; r++) {
                int ml = t * 16 + quad * 4 + r;
                float v = (ac[t][jt][r] + bf2f(sRect[ml * 524 + j])) * 0.125f;
                ac[t][jt][r] = v;
                rmax[t][r] = fmaxf(rmax[t][r], v);
            }
    }
#pragma unroll
    for (int o = 1; o <= 8; o <<= 1)
#pragma unroll
        for (int t = 0; t < 2; t++)
#pragma unroll
            for (int r = 0; r < 4; r++) rmax[t][r] = fmaxf(rmax[t][r], __shfl_xor(rmax[t][r], o));
    if (col == 0)
#pragma unroll
        for (int t = 0; t < 2; t++)
#pragma unroll
            for (int r = 0; r < 4; r++) sRed[(t * 16 + quad * 4 + r) * 4 + w] = rmax[t][r];
    __syncthreads();
    float gmax[2][4], psum[2][4];
#pragma unroll
    for (int t = 0; t < 2; t++)
#pragma unroll
        for (int r = 0; r < 4; r++) {
            int ml = t * 16 + quad * 4 + r;
            gmax[t][r] = fmaxf(fmaxf(sRed[ml * 4 + 0], sRed[ml * 4 + 1]),
                               fmaxf(sRed[ml * 4 + 2], sRed[ml * 4 + 3]));
            psum[t][r] = 0.f;
        }
    __syncthreads();
#pragma unroll
    for (int jt = 0; jt < 8; jt++)
#pragma unroll
        for (int t = 0; t < 2; t++)
#pragma unroll
            for (int r = 0; r < 4; r++) {
                float e = __expf(ac[t][jt][r] - gmax[t][r]);
                ac[t][jt][r] = e;
                psum[t][r] += e;
            }
#pragma unroll
    for (int o = 1; o <= 8; o <<= 1)
#pragma unroll
        for (int t = 0; t < 2; t++)
#pragma unroll
            for (int r = 0; r < 4; r++) psum[t][r] += __shfl_xor(psum[t][r], o);
    if (col == 0)
#pragma unroll
        for (int t = 0; t < 2; t++)
#pragma unroll
            for (int r = 0; r < 4; r++) sRed[(t * 16 + quad * 4 + r) * 4 + w] = psum[t][r];
    __syncthreads();
    float rinv[2][4];
#pragma unroll
    for (int t = 0; t < 2; t++)
#pragma unroll
        for (int r = 0; r < 4; r++) {
            int ml = t * 16 + quad * 4 + r;
            rinv[t][r] = 1.f / (sRed[ml * 4 + 0] + sRed[ml * 4 + 1] + sRed[ml * 4 + 2] + sRed[ml * 4 + 3]);
        }

    // ---- phase 4: probs -> sP (stride 520; sRect reads are >=2 barriers past) ----
#pragma unroll
    for (int jt = 0; jt < 8; jt++) {
        int j = (w << 7) + jt * 16 + col;
#pragma unroll
        for (int t = 0; t < 2; t++)
#pragma unroll
            for (int r = 0; r < 4; r++)
                sP[(t * 16 + quad * 4 + r) * 520 + j] = f2bf(ac[t][jt][r] * rinv[t][r]);
    }
    __syncthreads();

    // ---- phase 5: ctx(32x64) = P(32x512) . V^T, V fragments direct from L2 ----
    f32x4 cacc[2];
    cacc[0] = (f32x4){0.f, 0.f, 0.f, 0.f};
    cacc[1] = (f32x4){0.f, 0.f, 0.f, 0.f};
    {
        const u16* vp = Vz + ((size_t)((w << 4) + col) << 9) + quad * 8;
#pragma unroll
        for (int kc = 0; kc < 2; kc++)
#pragma unroll
            for (int s2 = 0; s2 < 8; s2++) {
                int ko = (kc << 8) + (s2 << 5);
                bf16x8 a0 = *(const bf16x8*)(sP + col * 520 + ko + quad * 8);
                bf16x8 a1 = *(const bf16x8*)(sP + (col + 16) * 520 + ko + quad * 8);
                bf16x8 bfr = *(const bf16x8*)(vp + ko);
                cacc[0] = __builtin_amdgcn_mfma_f32_16x16x32_bf16(a0, bfr, cacc[0], 0, 0, 0);
                cacc[1] = __builtin_amdgcn_mfma_f32_16x16x32_bf16(a1, bfr, cacc[1], 0, 0, 0);
            }
    }

    // ---- phase 6: ctx tile -> LDS (disjoint region) -> coalesced 16B stores ----
#pragma unroll
    for (int t = 0; t < 2; t++)
#pragma unroll
        for (int r = 0; r < 4; r++)
            sCtx[(t * 16 + quad * 4 + r) * 64 + (w << 4) + col] = f2bf(cacc[t][r]);
    __syncthreads();
    {
        int row = tid >> 3, seg = tid & 7;
        u16* dst = ctx + (((size_t)((m0 + row) * 16 + nb)) << 9) + (h << 6) + seg * 8;
        *(uint4*)dst = *(const uint4*)(sCtx + row * 64 + seg * 8);
    }
}

// ---------- repack qkv: vectorized, VT via LDS transpose (coalesced writes) ----------
__global__ __launch_bounds__(256) void repack_k(const u16* __restrict__ qkv,
                                                const float* __restrict__ bu,
                                                const float* __restrict__ bv,
                                                u16* __restrict__ QU, u16* __restrict__ QV,
                                                u16* __restrict__ Kb, u16* __restrict__ VT) {
    __shared__ u16 sV[64 * 72];  // 9216 B, stride 72 (8-aligned, bank step 4)
    int nh = blockIdx.x, h = nh & 7, n = nh >> 3;
    int l0 = blockIdx.y << 6;
    int tid = threadIdx.x;
    int d8 = (tid & 7) << 3;
    float bub[8], bvb[8];
#pragma unroll
    for (int e = 0; e < 8; e++) {
        bub[e] = bu[h * 64 + d8 + e];
        bvb[e] = bv[h * 64 + d8 + e];
    }
#pragma unroll
    for (int rep = 0; rep < 2; rep++) {
        int ll = (tid >> 3) + rep * 32;
        int l = l0 + ll;
        size_t base = (size_t)(l * 16 + n) * 1536 + h * 64 + d8;
        u16x8 q = *(const u16x8*)(qkv + base);
        u16x8 k = *(const u16x8*)(qkv + base + 512);
        u16x8 v = *(const u16x8*)(qkv + base + 1024);
        u16x8 qu, qv;
#pragma unroll
        for (int e = 0; e < 8; e++) {
            float qf = bf2f(q[e]);
            qu[e] = f2bf(qf + bub[e]);
            qv[e] = f2bf(qf + bvb[e]);
        }
        size_t o = ((size_t)nh * 512 + l) * 64 + d8;
        *(u16x8*)(QU + o) = qu;
        *(u16x8*)(QV + o) = qv;
        *(u16x8*)(Kb + o) = k;
        *(u16x8*)(sV + ll * 72 + d8) = v;
    }
    __syncthreads();
    int d = tid >> 2, ls = (tid & 3) << 4;
    u16 tmp[16];
#pragma unroll
    for (int e = 0; e < 16; e++) tmp[e] = sV[(ls + e) * 72 + d];
    u16* dst = VT + ((size_t)nh * 64 + d) * 512 + l0 + ls;
    *(u16x8*)(dst) = *(const u16x8*)(tmp);
    *(u16x8*)(dst + 8) = *(const u16x8*)(tmp + 8);
}

// ---------- depthwise conv: sliding window, 16 outputs per thread ----------
__global__ __launch_bounds__(256) void dwconv_k(
    const u16* __restrict__ g, const float* __restrict__ w, const float* __restrict__ wb,
    const float* __restrict__ bng, const float* __restrict__ bnb, const float* __restrict__ bnm,
    const float* __restrict__ bnv, u16* __restrict__ out) {
    int idx = blockIdx.x * 256 + threadIdx.x;  // 262144 threads
    int c = idx & 511;
    int t = idx >> 9;
    int n = t & 15, l0 = (t >> 4) << 4;
    float win[46];
#pragma unroll
    for (int q = 0; q < 46; q++) {
        int ll = l0 - 15 + q;
        win[q] = (ll >= 0 && ll < 512) ? bf2f(g[((size_t)(ll * 16 + n) << 9) + c]) : 0.f;
    }
    float wgt[31];
#pragma unroll
    for (int k = 0; k < 31; k++) wgt[k] = w[c * 31 + k];
    float ivg = rsqrtf(bnv[c] + 1e-5f) * bng[c];
    float mc = bnm[c], bc = bnb[c], wbc = wb[c];
#pragma unroll
    for (int r = 0; r < 16; r++) {
        float acc = 0.f;
#pragma unroll
        for (int k = 0; k < 31; k++) acc += wgt[k] * win[r + k];
        acc += wbc;
        float y = (acc - mc) * ivg + bc;
        y = y * sigm(y);
        out[((size_t)((l0 + r) * 16 + n) << 9) + c] = f2bf(y);
    }
}

// ---------- launch ----------
extern "C" void kernel_launch(void* const* d_in, const int* in_sizes, int n_in,
                              void* d_out, int out_size, void* d_ws, size_t ws_size,
                              hipStream_t stream) {
    const float* src      = (const float*)d_in[0];
    const float* pos_emb  = (const float*)d_in[1];
    const float* ffm_w1   = (const float*)d_in[2];
    const float* ffm_b1   = (const float*)d_in[3];
    const float* ffm_w2   = (const float*)d_in[4];
    const float* ffm_b2   = (const float*)d_in[5];
    const float* ff_w1    = (const float*)d_in[6];
    const float* ff_b1    = (const float*)d_in[7];
    const float* ff_w2    = (const float*)d_in[8];
    const float* ff_b2    = (const float*)d_in[9];
    const float* in_w     = (const float*)d_in[10];
    const float* in_b     = (const float*)d_in[11];
    const float* out_w    = (const float*)d_in[12];
    const float* out_b    = (const float*)d_in[13];
    const float* pos_w    = (const float*)d_in[14];
    const float* bu       = (const float*)d_in[15];
    const float* bv       = (const float*)d_in[16];
    const float* pw1_w    = (const float*)d_in[17];
    const float* pw1_b    = (const float*)d_in[18];
    const float* dw_w     = (const float*)d_in[19];
    const float* dw_b     = (const float*)d_in[20];
    const float* bng      = (const float*)d_in[21];
    const float* bnb      = (const float*)d_in[22];
    const float* bnm      = (const float*)d_in[23];
    const float* bnv      = (const float*)d_in[24];
    const float* pw2_w    = (const float*)d_in[25];
    const float* pw2_b    = (const float*)d_in[26];
    const float* ln_ffm_g = (const float*)d_in[27];
    const float* ln_ffm_b = (const float*)d_in[28];
    const float* ln_mha_g = (const float*)d_in[29];
    const float* ln_mha_b = (const float*)d_in[30];
    const float* ln_cv_g  = (const float*)d_in[31];
    const float* ln_cv_b  = (const float*)d_in[32];
    const float* ln_ff_g  = (const float*)d_in[33];
    const float* ln_ff_b  = (const float*)d_in[34];
    const float* ln_fin_g = (const float*)d_in[35];
    const float* ln_fin_b = (const float*)d_in[36];
    (void)in_sizes; (void)n_in; (void)out_size; (void)ws_size;

    // ---- workspace layout in u16 units; total ~117 MiB ----
    const size_t MEG = 1048576;
    u16* U = (u16*)d_ws;
    float* xA = (float*)U;                // 8M u16; Pbf aliases during attention
    u16* Pbf = U;                         // 524288 u16 (8 x 1024 x 64)
    float* xB = (float*)(U + 8 * MEG);    // 8M
    u16* LNB = U + 16 * MEG;              // 4M
    u16* BIG = U + 20 * MEG;              // 16M: h1 / qkv
    u16* QU = U + 36 * MEG;               // 4M
    u16* QV = U + 40 * MEG;               // 4M
    u16* Kb = U + 44 * MEG;               // 4M
    u16* VT = U + 48 * MEG;               // 4M
    u16* WB = U + 52 * MEG;               // 6,815,232 weights bf16
    u16* w_ffm1 = WB;
    u16* w_ffm2 = WB + 1 * MEG;
    u16* w_ff1  = WB + 2 * MEG;
    u16* w_ff2  = WB + 3 * MEG;
    u16* w_in   = WB + 4 * MEG;
    u16* w_out  = WB + 4 * MEG + 786432;
    u16* w_pw1  = WB + 5 * MEG;
    u16* w_pw2  = WB + 5 * MEG + 524288;
    u16* w_pos  = WB + 6029312;           // 512x512
    u16* w_pe   = WB + 6291456;           // 1023x512
    u16* CTX = LNB;
    u16* GLU = QU;
    u16* CACT = QV;

    // ---- cast all weights + pos inputs to bf16 (one dispatch) ----
    castall_k<<<26622, 256, 0, stream>>>(ffm_w1, ffm_w2, ff_w1, ff_w2, in_w, out_w,
                                         pw1_w, pw2_w, pos_w, pos_emb, WB);

    // ---- FFN macaron: xB = src + 0.5*ffn(ln(src)) ----
    ln512_k<true><<<2048, 256, 0, stream>>>(src, ln_ffm_g, ln_ffm_b, LNB);
    mgemmsk_k<<<dim3(128, 32), 128, 0, stream>>>(LNB, w_ffm1, ffm_b1, nullptr, BIG,
                                                 8192, 2048, 512, 0.f, 1, 1);
    mgemmsk_k<<<dim3(128, 8), 128, 0, stream>>>(BIG, w_ffm2, ffm_b2, src, xB,
                                                8192, 512, 2048, 0.5f, 0, 0);

    // ---- attention: xA = xB + attn(ln(xB)) ----
    ln512_k<true><<<2048, 256, 0, stream>>>(xB, ln_mha_g, ln_mha_b, LNB);
    posb_k<<<dim3(8, 4), 256, 0, stream>>>(w_pe, w_pos, Pbf);
    mgemmsk_k<<<dim3(128, 24), 128, 0, stream>>>(LNB, w_in, in_b, nullptr, BIG,
                                                 8192, 1536, 512, 0.f, 0, 1);
    repack_k<<<dim3(128, 8), 256, 0, stream>>>(BIG, bu, bv, QU, QV, Kb, VT);
    fattn_k<<<dim3(128, 16), 256, 0, stream>>>(QU, QV, Kb, Pbf, VT, CTX);
    mgemmsk_k<<<dim3(128, 8), 128, 0, stream>>>(CTX, w_out, out_b, xB, xA,
                                                8192, 512, 512, 1.f, 0, 0);

    // ---- conv module: xB = xA + conv(ln(xA)) ----
    ln512_k<true><<<2048, 256, 0, stream>>>(xA, ln_cv_g, ln_cv_b, LNB);
    mgemmglu_k<<<dim3(128, 8), 256, 0, stream>>>(LNB, w_pw1, pw1_b, GLU, 512);
    dwconv_k<<<1024, 256, 0, stream>>>(GLU, dw_w, dw_b, bng, bnb, bnm, bnv, CACT);
    mgemmsk_k<<<dim3(128, 8), 128, 0, stream>>>(CACT, w_pw2, pw2_b, xA, xB,
                                                8192, 512, 512, 1.f, 0, 0);

    // ---- FFN 2: xA = xB + 0.5*ffn(ln(xB)) ----
    ln512_k<true><<<2048, 256, 0, stream>>>(xB, ln_ff_g, ln_ff_b, LNB);
    mgemmsk_k<<<dim3(128, 32), 128, 0, stream>>>(LNB, w_ff1, ff_b1, nullptr, BIG,
                                                 8192, 2048, 512, 0.f, 1, 1);
    mgemmsk_k<<<dim3(128, 8), 128, 0, stream>>>(BIG, w_ff2, ff_b2, xB, xA,
                                                8192, 512, 2048, 0.5f, 0, 0);

    // ---- final LN -> fp32 out ----
    ln512_k<false><<<2048, 256, 0, stream>>>(xA, ln_fin_g, ln_fin_b, (float*)d_out);
}

// Round 9
// 512.059 us; speedup vs baseline: 1.2458x; 1.2458x over previous
//
#include <hip/hip_runtime.h>
#include <cstdint>
#include <cstddef>

typedef unsigned short u16;
typedef __attribute__((ext_vector_type(4))) float f32x4;
typedef __attribute__((ext_vector_type(8))) short bf16x8;
typedef __attribute__((ext_vector_type(8))) unsigned short u16x8;

// ---------- helpers ----------
__device__ __forceinline__ float sigm(float x) { return 1.f / (1.f + __expf(-x)); }
__device__ __forceinline__ float bf2f(u16 u) {
    union { unsigned int i; float f; } c; c.i = ((unsigned int)u) << 16; return c.f;
}
__device__ __forceinline__ u16 f2bf(float f) {
    union { float f; unsigned int i; } c; c.f = f;
    unsigned int x = c.i;
    x += 0x7fffu + ((x >> 16) & 1u);
    return (u16)(x >> 16);
}

// dims: D=512, H=8, DH=64, F=2048, K=31, L=512, N=16, M=8192

// ---------- fused weight cast fp32 -> bf16, float4 vectorized (R8) ----------
// All 10 array boundaries are multiples of 4 -> a 4-group never straddles arrays.
__global__ void castall_k(const float* __restrict__ s0, const float* __restrict__ s1,
                          const float* __restrict__ s2, const float* __restrict__ s3,
                          const float* __restrict__ s4, const float* __restrict__ s5,
                          const float* __restrict__ s6, const float* __restrict__ s7,
                          const float* __restrict__ s8, const float* __restrict__ s9,
                          u16* __restrict__ dst) {
    int i = (blockIdx.x * 256 + threadIdx.x) << 2;
    if (i >= 6815232) return;
    const float* s; int off;
    if      (i < 1048576) { s = s0; off = 0; }
    else if (i < 2097152) { s = s1; off = 1048576; }
    else if (i < 3145728) { s = s2; off = 2097152; }
    else if (i < 4194304) { s = s3; off = 3145728; }
    else if (i < 4980736) { s = s4; off = 4194304; }
    else if (i < 5242880) { s = s5; off = 4980736; }
    else if (i < 5767168) { s = s6; off = 5242880; }
    else if (i < 6029312) { s = s7; off = 5767168; }
    else if (i < 6291456) { s = s8; off = 6029312; }
    else                  { s = s9; off = 6291456; }
    float4 v = *(const float4*)(s + (i - off));
    union { unsigned int u[2]; } o;
    o.u[0] = (unsigned int)f2bf(v.x) | ((unsigned int)f2bf(v.y) << 16);
    o.u[1] = (unsigned int)f2bf(v.z) | ((unsigned int)f2bf(v.w) << 16);
    *(uint2*)(dst + i) = *(const uint2*)o.u;
}

// ---------- LayerNorm over 512 (fp32 in), 4 rows per 256-thread block ----------
template <bool OUTBF>
__global__ __launch_bounds__(256) void ln512_k(const float* __restrict__ x,
                                               const float* __restrict__ g,
                                               const float* __restrict__ b,
                                               void* __restrict__ outv) {
    int row = blockIdx.x * 4 + (threadIdx.x >> 6);
    int lane = threadIdx.x & 63;
    const float* xr = x + (size_t)row * 512 + lane * 8;
    float4 v0 = *(const float4*)(xr);
    float4 v1 = *(const float4*)(xr + 4);
    float va[8] = {v0.x, v0.y, v0.z, v0.w, v1.x, v1.y, v1.z, v1.w};
    float s = 0.f;
#pragma unroll
    for (int t = 0; t < 8; t++) s += va[t];
#pragma unroll
    for (int o = 32; o > 0; o >>= 1) s += __shfl_xor(s, o);
    float m = s * (1.0f / 512.0f);
    float q = 0.f;
#pragma unroll
    for (int t = 0; t < 8; t++) { float d = va[t] - m; q += d * d; }
#pragma unroll
    for (int o = 32; o > 0; o >>= 1) q += __shfl_xor(q, o);
    float inv = rsqrtf(q * (1.0f / 512.0f) + 1e-5f);
    int cb = lane * 8;
    if (OUTBF) {
        u16* o = (u16*)outv + (size_t)row * 512 + cb;
#pragma unroll
        for (int t = 0; t < 8; t++)
            o[t] = f2bf((va[t] - m) * inv * g[cb + t] + b[cb + t]);
    } else {
        float* o = (float*)outv + (size_t)row * 512 + cb;
#pragma unroll
        for (int t = 0; t < 8; t++)
            o[t] = (va[t] - m) * inv * g[cb + t] + b[cb + t];
    }
}

// ---------- MFMA GEMM 64x64 tile: occupancy kernel (R6 win; R7-best config) ----------
__global__ __launch_bounds__(256) void mgemm64_k(
    const u16* __restrict__ A, const u16* __restrict__ B, const float* __restrict__ bias,
    const float* __restrict__ add, void* __restrict__ Cv,
    int M, int Nn, int Kk, float coef, int act, int outbf) {
    __shared__ u16 lA[2][2048];
    __shared__ u16 lB[2][2048];
    int tid = threadIdx.x;
    int lane = tid & 63;
    int w = tid >> 6;
    int quad = lane >> 4, rl = lane & 15;
    int wm = (w >> 1) * 32, wn = (w & 1) * 32;
    int m0 = blockIdx.x << 6, n0 = blockIdx.y << 6;

    f32x4 acc[2][2];
#pragma unroll
    for (int i = 0; i < 2; i++)
#pragma unroll
        for (int j = 0; j < 2; j++) acc[i][j] = (f32x4){0.f, 0.f, 0.f, 0.f};

    int srow = tid >> 2;          // 0..63
    int scol = (tid & 3) << 3;    // 0,8,16,24
    const u16* gA = A + (size_t)(m0 + srow) * Kk + scol;
    const u16* gB = B + (size_t)(n0 + srow) * Kk + scol;
    int lso = tid * 8;
    int lra = wm * 32 + rl * 32 + quad * 8;   // row-stride 32 u16 (64B)
    int lrb = wn * 32 + rl * 32 + quad * 8;

    auto STAGE = [&](int buf, int k0) {
        __builtin_amdgcn_global_load_lds(
            (const __attribute__((address_space(1))) void*)(gA + k0),
            (__attribute__((address_space(3))) void*)(lA[buf] + lso), 16, 0, 0);
        __builtin_amdgcn_global_load_lds(
            (const __attribute__((address_space(1))) void*)(gB + k0),
            (__attribute__((address_space(3))) void*)(lB[buf] + lso), 16, 0, 0);
    };
    auto COMP = [&](int buf) {
        bf16x8 af[2], bf[2];
#pragma unroll
        for (int t = 0; t < 2; t++) {
            af[t] = *(const bf16x8*)(lA[buf] + lra + t * 512);
            bf[t] = *(const bf16x8*)(lB[buf] + lrb + t * 512);
        }
#pragma unroll
        for (int i = 0; i < 2; i++)
#pragma unroll
            for (int j = 0; j < 2; j++)
                acc[i][j] = __builtin_amdgcn_mfma_f32_16x16x32_bf16(af[i], bf[j], acc[i][j], 0, 0, 0);
    };

    int nk = Kk >> 5;
    STAGE(0, 0);
    __syncthreads();
    for (int kt = 1; kt < nk; kt++) {
        STAGE(kt & 1, kt << 5);
        COMP((kt - 1) & 1);
        __syncthreads();
    }
    COMP((nk - 1) & 1);

    int rbase = quad * 4;
#pragma unroll
    for (int i = 0; i < 2; i++) {
#pragma unroll
        for (int j = 0; j < 2; j++) {
            int n = n0 + wn + j * 16 + rl;
            float bv = bias ? bias[n] : 0.f;
#pragma unroll
            for (int r = 0; r < 4; r++) {
                int m = m0 + wm + i * 16 + rbase + r;
                float c = acc[i][j][r] + bv;
                if (act == 1) c *= sigm(c);
                size_t o = (size_t)m * Nn + n;
                if (add) c = add[o] + coef * c;
                if (outbf) ((u16*)Cv)[o] = f2bf(c);
                else ((float*)Cv)[o] = c;
            }
        }
    }
}

// ---------- pw1 GEMM with fused GLU epilogue: out(M,512) = a * sigm(gate) (R7 win) ----------
__global__ __launch_bounds__(256) void mgemmglu_k(
    const u16* __restrict__ A, const u16* __restrict__ B, const float* __restrict__ bias,
    u16* __restrict__ Cv, int Kk) {
    __shared__ u16 lA[2][2048];
    __shared__ u16 lBa[2][2048];
    __shared__ u16 lBg[2][2048];
    int tid = threadIdx.x;
    int lane = tid & 63;
    int w = tid >> 6;
    int quad = lane >> 4, rl = lane & 15;
    int wm = (w >> 1) * 32, wn = (w & 1) * 32;
    int m0 = blockIdx.x << 6, n0 = blockIdx.y << 6;

    f32x4 accA[2][2], accG[2][2];
#pragma unroll
    for (int i = 0; i < 2; i++)
#pragma unroll
        for (int j = 0; j < 2; j++) {
            accA[i][j] = (f32x4){0.f, 0.f, 0.f, 0.f};
            accG[i][j] = (f32x4){0.f, 0.f, 0.f, 0.f};
        }

    int srow = tid >> 2;
    int scol = (tid & 3) << 3;
    const u16* gA  = A + (size_t)(m0 + srow) * Kk + scol;
    const u16* gBa = B + (size_t)(n0 + srow) * Kk + scol;
    const u16* gBg = B + (size_t)(512 + n0 + srow) * Kk + scol;
    int lso = tid * 8;
    int lra = wm * 32 + rl * 32 + quad * 8;
    int lrb = wn * 32 + rl * 32 + quad * 8;

    auto STAGE = [&](int buf, int k0) {
        __builtin_amdgcn_global_load_lds(
            (const __attribute__((address_space(1))) void*)(gA + k0),
            (__attribute__((address_space(3))) void*)(lA[buf] + lso), 16, 0, 0);
        __builtin_amdgcn_global_load_lds(
            (const __attribute__((address_space(1))) void*)(gBa + k0),
            (__attribute__((address_space(3))) void*)(lBa[buf] + lso), 16, 0, 0);
        __builtin_amdgcn_global_load_lds(
            (const __attribute__((address_space(1))) void*)(gBg + k0),
            (__attribute__((address_space(3))) void*)(lBg[buf] + lso), 16, 0, 0);
    };
    auto COMP = [&](int buf) {
        bf16x8 af[2], ba[2], bg[2];
#pragma unroll
        for (int t = 0; t < 2; t++) {
            af[t] = *(const bf16x8*)(lA[buf] + lra + t * 512);
            ba[t] = *(const bf16x8*)(lBa[buf] + lrb + t * 512);
            bg[t] = *(const bf16x8*)(lBg[buf] + lrb + t * 512);
        }
#pragma unroll
        for (int i = 0; i < 2; i++)
#pragma unroll
            for (int j = 0; j < 2; j++) {
                accA[i][j] = __builtin_amdgcn_mfma_f32_16x16x32_bf16(af[i], ba[j], accA[i][j], 0, 0, 0);
                accG[i][j] = __builtin_amdgcn_mfma_f32_16x16x32_bf16(af[i], bg[j], accG[i][j], 0, 0, 0);
            }
    };

    int nk = Kk >> 5;
    STAGE(0, 0);
    __syncthreads();
    for (int kt = 1; kt < nk; kt++) {
        STAGE(kt & 1, kt << 5);
        COMP((kt - 1) & 1);
        __syncthreads();
    }
    COMP((nk - 1) & 1);

    int rbase = quad * 4;
#pragma unroll
    for (int i = 0; i < 2; i++) {
#pragma unroll
        for (int j = 0; j < 2; j++) {
            int n = n0 + wn + j * 16 + rl;
            float bva = bias[n], bvg = bias[512 + n];
#pragma unroll
            for (int r = 0; r < 4; r++) {
                int m = m0 + wm + i * 16 + rbase + r;
                float a = accA[i][j][r] + bva;
                float g = accG[i][j][r] + bvg;
                Cv[(size_t)m * 512 + n] = f2bf(a * sigm(g));
            }
        }
    }
}

// ---------- pos GEMM 64x64 (R8): Pbf[h][m][d] = pos_emb(1023x512) @ pos_w^T ----------
// Old posb_k had grid 32 blocks (1/8 of CUs). 64x64 tiles -> grid (16,8)=128 blocks.
// A rows clamped at 1022; m==1023 writes 0 (fattn reads row 1023 when m0=0).
__global__ __launch_bounds__(256) void posb64_k(const u16* __restrict__ A,
                                                const u16* __restrict__ B,
                                                u16* __restrict__ Pbf) {
    __shared__ u16 lA[2][2048];
    __shared__ u16 lB[2][2048];
    const int Kk = 512;
    int tid = threadIdx.x;
    int lane = tid & 63;
    int w = tid >> 6;
    int quad = lane >> 4, rl = lane & 15;
    int wm = (w >> 1) * 32, wn = (w & 1) * 32;
    int m0 = blockIdx.x << 6, n0 = blockIdx.y << 6;

    f32x4 acc[2][2];
#pragma unroll
    for (int i = 0; i < 2; i++)
#pragma unroll
        for (int j = 0; j < 2; j++) acc[i][j] = (f32x4){0.f, 0.f, 0.f, 0.f};

    int srow = tid >> 2;
    int scol = (tid & 3) << 3;
    int ar = m0 + srow; if (ar > 1022) ar = 1022;
    const u16* gA = A + (size_t)ar * Kk + scol;
    const u16* gB = B + (size_t)(n0 + srow) * Kk + scol;
    int lso = tid * 8;
    int lra = wm * 32 + rl * 32 + quad * 8;
    int lrb = wn * 32 + rl * 32 + quad * 8;

    auto STAGE = [&](int buf, int k0) {
        __builtin_amdgcn_global_load_lds(
            (const __attribute__((address_space(1))) void*)(gA + k0),
            (__attribute__((address_space(3))) void*)(lA[buf] + lso), 16, 0, 0);
        __builtin_amdgcn_global_load_lds(
            (const __attribute__((address_space(1))) void*)(gB + k0),
            (__attribute__((address_space(3))) void*)(lB[buf] + lso), 16, 0, 0);
    };
    auto COMP = [&](int buf) {
        bf16x8 af[2], bf[2];
#pragma unroll
        for (int t = 0; t < 2; t++) {
            af[t] = *(const bf16x8*)(lA[buf] + lra + t * 512);
            bf[t] = *(const bf16x8*)(lB[buf] + lrb + t * 512);
        }
#pragma unroll
        for (int i = 0; i < 2; i++)
#pragma unroll
            for (int j = 0; j < 2; j++)
                acc[i][j] = __builtin_amdgcn_mfma_f32_16x16x32_bf16(af[i], bf[j], acc[i][j], 0, 0, 0);
    };

    int nk = Kk >> 5;
    STAGE(0, 0);
    __syncthreads();
    for (int kt = 1; kt < nk; kt++) {
        STAGE(kt & 1, kt << 5);
        COMP((kt - 1) & 1);
        __syncthreads();
    }
    COMP((nk - 1) & 1);

    int rbase = quad * 4;
#pragma unroll
    for (int i = 0; i < 2; i++) {
#pragma unroll
        for (int j = 0; j < 2; j++) {
            int n = n0 + wn + j * 16 + rl;
            int h = n >> 6, d = n & 63;
#pragma unroll
            for (int r = 0; r < 4; r++) {
                int m = m0 + wm + i * 16 + rbase + r;
                u16 val = (m < 1023) ? f2bf(acc[i][j][r]) : (u16)0;
                Pbf[(((size_t)(h * 1024 + m)) << 6) + d] = val;
            }
        }
    }
}

// ---------- fused flash attention v2 (best measured) ----------
__global__ __launch_bounds__(256) void fattn_k(
    const u16* __restrict__ QU, const u16* __restrict__ QV,
    const u16* __restrict__ Kb, const u16* __restrict__ Pbf,
    const u16* __restrict__ VT, u16* __restrict__ ctx) {
    __shared__ u16 arr[19072];            // 38,144 B -> 4 blocks/CU by LDS
    u16* sRect = arr;                     // bd shifted: 32 rows x stride 524 (scalar acc)
    u16* sP = arr;                        // alias: probs 32 x stride 520 (b128 reads)
    u16* sCtx = arr + 16768;              // 32 x 64 (disjoint from sP)
    float* sRed = (float*)(arr + 18816);  // 32 x 4 floats

    int tid = threadIdx.x;
    int lane = tid & 63, w = tid >> 6;
    int quad = lane >> 4, col = lane & 15;
    int nh = blockIdx.x, h = nh & 7, nb = nh >> 3;
    int m0 = blockIdx.y << 5;             // 32 q-rows per block
    int nlo = 480 - m0;                   // P window: rows nlo..nlo+543 (<=1023)

    const u16* QVz = QV + ((size_t)nh << 15);
    const u16* QUz = QU + ((size_t)nh << 15);
    const u16* Kz  = Kb + ((size_t)nh << 15);
    const u16* Vz  = VT + ((size_t)nh << 15);
    const u16* Pb  = Pbf + ((size_t)h << 16);

    // ---- phase 1: bd(32x544) = QV_tile . P^T, per-tile accumulators retired to sRect ----
    bf16x8 av[2][2];
#pragma unroll
    for (int ks = 0; ks < 2; ks++)
#pragma unroll
        for (int t = 0; t < 2; t++)
            av[ks][t] = *(const bf16x8*)(QVz + ((size_t)(m0 + t * 16 + col) << 6) + (ks << 5) + quad * 8);
#pragma unroll
    for (int idx = 0; idx < 9; idx++) {
        int nt = w + (idx << 2);
        if (nt < 34) {
            int crow = nt * 16 + col;
            const u16* pb = Pb + ((size_t)(nlo + crow) << 6) + quad * 8;
            f32x4 b0 = (f32x4){0.f, 0.f, 0.f, 0.f};
            f32x4 b1 = (f32x4){0.f, 0.f, 0.f, 0.f};
#pragma unroll
            for (int ks = 0; ks < 2; ks++) {
                bf16x8 bfr = *(const bf16x8*)(pb + (ks << 5));
                b0 = __builtin_amdgcn_mfma_f32_16x16x32_bf16(av[ks][0], bfr, b0, 0, 0, 0);
                b1 = __builtin_amdgcn_mfma_f32_16x16x32_bf16(av[ks][1], bfr, b1, 0, 0, 0);
            }
            // shifted write: rect col c -> j = c + ml - 31; stride 524
#pragma unroll
            for (int r = 0; r < 4; r++) {
                int ml0 = quad * 4 + r;
                int j0 = crow + ml0 - 31;
                if (j0 >= 0 && j0 < 512) sRect[ml0 * 524 + j0] = f2bf(b0[r]);
                int ml1 = ml0 + 16;
                int j1 = crow + ml1 - 31;
                if (j1 >= 0 && j1 < 512) sRect[ml1 * 524 + j1] = f2bf(b1[r]);
            }
        }
    }

    // ---- phase 2: ac(32x512) = QU_tile . K^T (direct reads, no barriers) ----
    bf16x8 au[2][2];
#pragma unroll
    for (int ks = 0; ks < 2; ks++)
#pragma unroll
        for (int t = 0; t < 2; t++)
            au[ks][t] = *(const bf16x8*)(QUz + ((size_t)(m0 + t * 16 + col) << 6) + (ks << 5) + quad * 8);
    f32x4 ac[2][8];
#pragma unroll
    for (int t = 0; t < 2; t++)
#pragma unroll
        for (int jt = 0; jt < 8; jt++) ac[t][jt] = (f32x4){0.f, 0.f, 0.f, 0.f};
#pragma unroll
    for (int jt = 0; jt < 8; jt++) {
        const u16* kp = Kz + ((size_t)((w << 7) + jt * 16 + col) << 6) + quad * 8;
#pragma unroll
        for (int ks = 0; ks < 2; ks++) {
            bf16x8 bfr = *(const bf16x8*)(kp + (ks << 5));
            ac[0][jt] = __builtin_amdgcn_mfma_f32_16x16x32_bf16(au[ks][0], bfr, ac[0][jt], 0, 0, 0);
            ac[1][jt] = __builtin_amdgcn_mfma_f32_16x16x32_bf16(au[ks][1], bfr, ac[1][jt], 0, 0, 0);
        }
    }
    __syncthreads();  // all sRect writes visible before phase-3 reads

    // ---- phase 3: shifted add + scale + softmax over j ----
    float rmax[2][4];
#pragma unroll
    for (int t = 0; t < 2; t++)
#pragma unroll
        for (int r = 0; r < 4; r++) rmax[t][r] = -1e30f;
#pragma unroll
    for (int jt = 0; jt < 8; jt++) {
        int j = (w << 7) + jt * 16 + col;
#pragma unroll
        for (int t = 0; t < 2; t++)
#pragma unroll
            for (int r = 0; r < 4; r++) {
                int ml = t * 16 + quad * 4 + r;
                float v = (ac[t][jt][r] + bf2f(sRect[ml * 524 + j])) * 0.125f;
                ac[t][jt][r] = v;
                rmax[t][r] = fmaxf(rmax[t][r], v);
            }
    }
#pragma unroll
    for (int o = 1; o <= 8; o <<= 1)
#pragma unroll
        for (int t = 0; t < 2; t++)
#pragma unroll
            for (int r = 0; r < 4; r++) rmax[t][r] = fmaxf(rmax[t][r], __shfl_xor(rmax[t][r], o));
    if (col == 0)
#pragma unroll
        for (int t = 0; t < 2; t++)
#pragma unroll
            for (int r = 0; r < 4; r++) sRed[(t * 16 + quad * 4 + r) * 4 + w] = rmax[t][r];
    __syncthreads();
    float gmax[2][4], psum[2][4];
#pragma unroll
    for (int t = 0; t < 2; t++)
#pragma unroll
        for (int r = 0; r < 4; r++) {
            int ml = t * 16 + quad * 4 + r;
            gmax[t][r] = fmaxf(fmaxf(sRed[ml * 4 + 0], sRed[ml * 4 + 1]),
                               fmaxf(sRed[ml * 4 + 2], sRed[ml * 4 + 3]));
            psum[t][r] = 0.f;
        }
    __syncthreads();
#pragma unroll
    for (int jt = 0; jt < 8; jt++)
#pragma unroll
        for (int t = 0; t < 2; t++)
#pragma unroll
            for (int r = 0; r < 4; r++) {
                float e = __expf(ac[t][jt][r] - gmax[t][r]);
                ac[t][jt][r] = e;
                psum[t][r] += e;
            }
#pragma unroll
    for (int o = 1; o <= 8; o <<= 1)
#pragma unroll
        for (int t = 0; t < 2; t++)
#pragma unroll
            for (int r = 0; r < 4; r++) psum[t][r] += __shfl_xor(psum[t][r], o);
    if (col == 0)
#pragma unroll
        for (int t = 0; t < 2; t++)
#pragma unroll
            for (int r = 0; r < 4; r++) sRed[(t * 16 + quad * 4 + r) * 4 + w] = psum[t][r];
    __syncthreads();
    float rinv[2][4];
#pragma unroll
    for (int t = 0; t < 2; t++)
#pragma unroll
        for (int r = 0; r < 4; r++) {
            int ml = t * 16 + quad * 4 + r;
            rinv[t][r] = 1.f / (sRed[ml * 4 + 0] + sRed[ml * 4 + 1] + sRed[ml * 4 + 2] + sRed[ml * 4 + 3]);
        }

    // ---- phase 4: probs -> sP (stride 520; sRect reads are >=2 barriers past) ----
#pragma unroll
    for (int jt = 0; jt < 8; jt++) {
        int j = (w << 7) + jt * 16 + col;
#pragma unroll
        for (int t = 0; t < 2; t++)
#pragma unroll
            for (int r = 0; r < 4; r++)
                sP[(t * 16 + quad * 4 + r) * 520 + j] = f2bf(ac[t][jt][r] * rinv[t][r]);
    }
    __syncthreads();

    // ---- phase 5: ctx(32x64) = P(32x512) . V^T, V fragments direct from L2 ----
    f32x4 cacc[2];
    cacc[0] = (f32x4){0.f, 0.f, 0.f, 0.f};
    cacc[1] = (f32x4){0.f, 0.f, 0.f, 0.f};
    {
        const u16* vp = Vz + ((size_t)((w << 4) + col) << 9) + quad * 8;
#pragma unroll
        for (int kc = 0; kc < 2; kc++)
#pragma unroll
            for (int s2 = 0; s2 < 8; s2++) {
                int ko = (kc << 8) + (s2 << 5);
                bf16x8 a0 = *(const bf16x8*)(sP + col * 520 + ko + quad * 8);
                bf16x8 a1 = *(const bf16x8*)(sP + (col + 16) * 520 + ko + quad * 8);
                bf16x8 bfr = *(const bf16x8*)(vp + ko);
                cacc[0] = __builtin_amdgcn_mfma_f32_16x16x32_bf16(a0, bfr, cacc[0], 0, 0, 0);
                cacc[1] = __builtin_amdgcn_mfma_f32_16x16x32_bf16(a1, bfr, cacc[1], 0, 0, 0);
            }
    }

    // ---- phase 6: ctx tile -> LDS (disjoint region) -> coalesced 16B stores ----
#pragma unroll
    for (int t = 0; t < 2; t++)
#pragma unroll
        for (int r = 0; r < 4; r++)
            sCtx[(t * 16 + quad * 4 + r) * 64 + (w << 4) + col] = f2bf(cacc[t][r]);
    __syncthreads();
    {
        int row = tid >> 3, seg = tid & 7;
        u16* dst = ctx + (((size_t)((m0 + row) * 16 + nb)) << 9) + (h << 6) + seg * 8;
        *(uint4*)dst = *(const uint4*)(sCtx + row * 64 + seg * 8);
    }
}

// ---------- repack qkv: vectorized, VT via LDS transpose (coalesced writes) ----------
__global__ __launch_bounds__(256) void repack_k(const u16* __restrict__ qkv,
                                                const float* __restrict__ bu,
                                                const float* __restrict__ bv,
                                                u16* __restrict__ QU, u16* __restrict__ QV,
                                                u16* __restrict__ Kb, u16* __restrict__ VT) {
    __shared__ u16 sV[64 * 72];  // 9216 B, stride 72 (8-aligned, bank step 4)
    int nh = blockIdx.x, h = nh & 7, n = nh >> 3;
    int l0 = blockIdx.y << 6;
    int tid = threadIdx.x;
    int d8 = (tid & 7) << 3;
    float bub[8], bvb[8];
#pragma unroll
    for (int e = 0; e < 8; e++) {
        bub[e] = bu[h * 64 + d8 + e];
        bvb[e] = bv[h * 64 + d8 + e];
    }
#pragma unroll
    for (int rep = 0; rep < 2; rep++) {
        int ll = (tid >> 3) + rep * 32;
        int l = l0 + ll;
        size_t base = (size_t)(l * 16 + n) * 1536 + h * 64 + d8;
        u16x8 q = *(const u16x8*)(qkv + base);
        u16x8 k = *(const u16x8*)(qkv + base + 512);
        u16x8 v = *(const u16x8*)(qkv + base + 1024);
        u16x8 qu, qv;
#pragma unroll
        for (int e = 0; e < 8; e++) {
            float qf = bf2f(q[e]);
            qu[e] = f2bf(qf + bub[e]);
            qv[e] = f2bf(qf + bvb[e]);
        }
        size_t o = ((size_t)nh * 512 + l) * 64 + d8;
        *(u16x8*)(QU + o) = qu;
        *(u16x8*)(QV + o) = qv;
        *(u16x8*)(Kb + o) = k;
        *(u16x8*)(sV + ll * 72 + d8) = v;
    }
    __syncthreads();
    int d = tid >> 2, ls = (tid & 3) << 4;
    u16 tmp[16];
#pragma unroll
    for (int e = 0; e < 16; e++) tmp[e] = sV[(ls + e) * 72 + d];
    u16* dst = VT + ((size_t)nh * 64 + d) * 512 + l0 + ls;
    *(u16x8*)(dst) = *(const u16x8*)(tmp);
    *(u16x8*)(dst + 8) = *(const u16x8*)(tmp + 8);
}

// ---------- depthwise conv: sliding window, 16 outputs per thread ----------
__global__ __launch_bounds__(256) void dwconv_k(
    const u16* __restrict__ g, const float* __restrict__ w, const float* __restrict__ wb,
    const float* __restrict__ bng, const float* __restrict__ bnb, const float* __restrict__ bnm,
    const float* __restrict__ bnv, u16* __restrict__ out) {
    int idx = blockIdx.x * 256 + threadIdx.x;  // 262144 threads
    int c = idx & 511;
    int t = idx >> 9;
    int n = t & 15, l0 = (t >> 4) << 4;
    float win[46];
#pragma unroll
    for (int q = 0; q < 46; q++) {
        int ll = l0 - 15 + q;
        win[q] = (ll >= 0 && ll < 512) ? bf2f(g[((size_t)(ll * 16 + n) << 9) + c]) : 0.f;
    }
    float wgt[31];
#pragma unroll
    for (int k = 0; k < 31; k++) wgt[k] = w[c * 31 + k];
    float ivg = rsqrtf(bnv[c] + 1e-5f) * bng[c];
    float mc = bnm[c], bc = bnb[c], wbc = wb[c];
#pragma unroll
    for (int r = 0; r < 16; r++) {
        float acc = 0.f;
#pragma unroll
        for (int k = 0; k < 31; k++) acc += wgt[k] * win[r + k];
        acc += wbc;
        float y = (acc - mc) * ivg + bc;
        y = y * sigm(y);
        out[((size_t)((l0 + r) * 16 + n) << 9) + c] = f2bf(y);
    }
}

// ---------- launch ----------
extern "C" void kernel_launch(void* const* d_in, const int* in_sizes, int n_in,
                              void* d_out, int out_size, void* d_ws, size_t ws_size,
                              hipStream_t stream) {
    const float* src      = (const float*)d_in[0];
    const float* pos_emb  = (const float*)d_in[1];
    const float* ffm_w1   = (const float*)d_in[2];
    const float* ffm_b1   = (const float*)d_in[3];
    const float* ffm_w2   = (const float*)d_in[4];
    const float* ffm_b2   = (const float*)d_in[5];
    const float* ff_w1    = (const float*)d_in[6];
    const float* ff_b1    = (const float*)d_in[7];
    const float* ff_w2    = (const float*)d_in[8];
    const float* ff_b2    = (const float*)d_in[9];
    const float* in_w     = (const float*)d_in[10];
    const float* in_b     = (const float*)d_in[11];
    const float* out_w    = (const float*)d_in[12];
    const float* out_b    = (const float*)d_in[13];
    const float* pos_w    = (const float*)d_in[14];
    const float* bu       = (const float*)d_in[15];
    const float* bv       = (const float*)d_in[16];
    const float* pw1_w    = (const float*)d_in[17];
    const float* pw1_b    = (const float*)d_in[18];
    const float* dw_w     = (const float*)d_in[19];
    const float* dw_b     = (const float*)d_in[20];
    const float* bng      = (const float*)d_in[21];
    const float* bnb      = (const float*)d_in[22];
    const float* bnm      = (const float*)d_in[23];
    const float* bnv      = (const float*)d_in[24];
    const float* pw2_w    = (const float*)d_in[25];
    const float* pw2_b    = (const float*)d_in[26];
    const float* ln_ffm_g = (const float*)d_in[27];
    const float* ln_ffm_b = (const float*)d_in[28];
    const float* ln_mha_g = (const float*)d_in[29];
    const float* ln_mha_b = (const float*)d_in[30];
    const float* ln_cv_g  = (const float*)d_in[31];
    const float* ln_cv_b  = (const float*)d_in[32];
    const float* ln_ff_g  = (const float*)d_in[33];
    const float* ln_ff_b  = (const float*)d_in[34];
    const float* ln_fin_g = (const float*)d_in[35];
    const float* ln_fin_b = (const float*)d_in[36];
    (void)in_sizes; (void)n_in; (void)out_size; (void)ws_size;

    // ---- workspace layout in u16 units; total ~117 MiB ----
    const size_t MEG = 1048576;
    u16* U = (u16*)d_ws;
    float* xA = (float*)U;                // 8M u16; Pbf aliases during attention
    u16* Pbf = U;                         // 524288 u16 (8 x 1024 x 64)
    float* xB = (float*)(U + 8 * MEG);    // 8M
    u16* LNB = U + 16 * MEG;              // 4M
    u16* BIG = U + 20 * MEG;              // 16M: h1 / qkv
    u16* QU = U + 36 * MEG;               // 4M
    u16* QV = U + 40 * MEG;               // 4M
    u16* Kb = U + 44 * MEG;               // 4M
    u16* VT = U + 48 * MEG;               // 4M
    u16* WB = U + 52 * MEG;               // 6,815,232 weights bf16
    u16* w_ffm1 = WB;
    u16* w_ffm2 = WB + 1 * MEG;
    u16* w_ff1  = WB + 2 * MEG;
    u16* w_ff2  = WB + 3 * MEG;
    u16* w_in   = WB + 4 * MEG;
    u16* w_out  = WB + 4 * MEG + 786432;
    u16* w_pw1  = WB + 5 * MEG;
    u16* w_pw2  = WB + 5 * MEG + 524288;
    u16* w_pos  = WB + 6029312;           // 512x512
    u16* w_pe   = WB + 6291456;           // 1023x512
    u16* CTX = LNB;
    u16* GLU = QU;
    u16* CACT = QV;

    // ---- cast all weights + pos inputs to bf16 (one dispatch, float4) ----
    castall_k<<<6656, 256, 0, stream>>>(ffm_w1, ffm_w2, ff_w1, ff_w2, in_w, out_w,
                                        pw1_w, pw2_w, pos_w, pos_emb, WB);

    // ---- FFN macaron: xB = src + 0.5*ffn(ln(src)) ----
    ln512_k<true><<<2048, 256, 0, stream>>>(src, ln_ffm_g, ln_ffm_b, LNB);
    mgemm64_k<<<dim3(128, 32), 256, 0, stream>>>(LNB, w_ffm1, ffm_b1, nullptr, BIG,
                                                 8192, 2048, 512, 0.f, 1, 1);
    mgemm64_k<<<dim3(128, 8), 256, 0, stream>>>(BIG, w_ffm2, ffm_b2, src, xB,
                                                8192, 512, 2048, 0.5f, 0, 0);

    // ---- attention: xA = xB + attn(ln(xB)) ----
    ln512_k<true><<<2048, 256, 0, stream>>>(xB, ln_mha_g, ln_mha_b, LNB);
    posb64_k<<<dim3(16, 8), 256, 0, stream>>>(w_pe, w_pos, Pbf);
    mgemm64_k<<<dim3(128, 24), 256, 0, stream>>>(LNB, w_in, in_b, nullptr, BIG,
                                                 8192, 1536, 512, 0.f, 0, 1);
    repack_k<<<dim3(128, 8), 256, 0, stream>>>(BIG, bu, bv, QU, QV, Kb, VT);
    fattn_k<<<dim3(128, 16), 256, 0, stream>>>(QU, QV, Kb, Pbf, VT, CTX);
    mgemm64_k<<<dim3(128, 8), 256, 0, stream>>>(CTX, w_out, out_b, xB, xA,
                                                8192, 512, 512, 1.f, 0, 0);

    // ---- conv module: xB = xA + conv(ln(xA)) ----
    ln512_k<true><<<2048, 256, 0, stream>>>(xA, ln_cv_g, ln_cv_b, LNB);
    mgemmglu_k<<<dim3(128, 8), 256, 0, stream>>>(LNB, w_pw1, pw1_b, GLU, 512);
    dwconv_k<<<1024, 256, 0, stream>>>(GLU, dw_w, dw_b, bng, bnb, bnm, bnv, CACT);
    mgemm64_k<<<dim3(128, 8), 256, 0, stream>>>(CACT, w_pw2, pw2_b, xA, xB,
                                                8192, 512, 512, 1.f, 0, 0);

    // ---- FFN 2: xA = xB + 0.5*ffn(ln(xB)) ----
    ln512_k<true><<<2048, 256, 0, stream>>>(xB, ln_ff_g, ln_ff_b, LNB);
    mgemm64_k<<<dim3(128, 32), 256, 0, stream>>>(LNB, w_ff1, ff_b1, nullptr, BIG,
                                                 8192, 2048, 512, 0.f, 1, 1);
    mgemm64_k<<<dim3(128, 8), 256, 0, stream>>>(BIG, w_ff2, ff_b2, xB, xA,
                                                8192, 512, 2048, 0.5f, 0, 0);

    // ---- final LN -> fp32 out ----
    ln512_k<false><<<2048, 256, 0, stream>>>(xA, ln_fin_g, ln_fin_b, (float*)d_out);
}

// Round 10
// 508.195 us; speedup vs baseline: 1.2552x; 1.0076x over previous
//
#include <hip/hip_runtime.h>
#include <cstdint>
#include <cstddef>

typedef unsigned short u16;
typedef __attribute__((ext_vector_type(4))) float f32x4;
typedef __attribute__((ext_vector_type(8))) short bf16x8;
typedef __attribute__((ext_vector_type(8))) unsigned short u16x8;

// ---------- helpers ----------
__device__ __forceinline__ float sigm(float x) { return 1.f / (1.f + __expf(-x)); }
__device__ __forceinline__ float bf2f(u16 u) {
    union { unsigned int i; float f; } c; c.i = ((unsigned int)u) << 16; return c.f;
}
__device__ __forceinline__ u16 f2bf(float f) {
    union { float f; unsigned int i; } c; c.f = f;
    unsigned int x = c.i;
    x += 0x7fffu + ((x >> 16) & 1u);
    return (u16)(x >> 16);
}

// dims: D=512, H=8, DH=64, F=2048, K=31, L=512, N=16, M=8192

// ---------- fused weight cast fp32 -> bf16, float4 vectorized (R8) ----------
__global__ void castall_k(const float* __restrict__ s0, const float* __restrict__ s1,
                          const float* __restrict__ s2, const float* __restrict__ s3,
                          const float* __restrict__ s4, const float* __restrict__ s5,
                          const float* __restrict__ s6, const float* __restrict__ s7,
                          const float* __restrict__ s8, const float* __restrict__ s9,
                          u16* __restrict__ dst) {
    int i = (blockIdx.x * 256 + threadIdx.x) << 2;
    if (i >= 6815232) return;
    const float* s; int off;
    if      (i < 1048576) { s = s0; off = 0; }
    else if (i < 2097152) { s = s1; off = 1048576; }
    else if (i < 3145728) { s = s2; off = 2097152; }
    else if (i < 4194304) { s = s3; off = 3145728; }
    else if (i < 4980736) { s = s4; off = 4194304; }
    else if (i < 5242880) { s = s5; off = 4980736; }
    else if (i < 5767168) { s = s6; off = 5242880; }
    else if (i < 6029312) { s = s7; off = 5767168; }
    else if (i < 6291456) { s = s8; off = 6029312; }
    else                  { s = s9; off = 6291456; }
    float4 v = *(const float4*)(s + (i - off));
    union { unsigned int u[2]; } o;
    o.u[0] = (unsigned int)f2bf(v.x) | ((unsigned int)f2bf(v.y) << 16);
    o.u[1] = (unsigned int)f2bf(v.z) | ((unsigned int)f2bf(v.w) << 16);
    *(uint2*)(dst + i) = *(const uint2*)o.u;
}

// ---------- LayerNorm over 512 (fp32 in), 4 rows per 256-thread block ----------
template <bool OUTBF>
__global__ __launch_bounds__(256) void ln512_k(const float* __restrict__ x,
                                               const float* __restrict__ g,
                                               const float* __restrict__ b,
                                               void* __restrict__ outv) {
    int row = blockIdx.x * 4 + (threadIdx.x >> 6);
    int lane = threadIdx.x & 63;
    const float* xr = x + (size_t)row * 512 + lane * 8;
    float4 v0 = *(const float4*)(xr);
    float4 v1 = *(const float4*)(xr + 4);
    float va[8] = {v0.x, v0.y, v0.z, v0.w, v1.x, v1.y, v1.z, v1.w};
    float s = 0.f;
#pragma unroll
    for (int t = 0; t < 8; t++) s += va[t];
#pragma unroll
    for (int o = 32; o > 0; o >>= 1) s += __shfl_xor(s, o);
    float m = s * (1.0f / 512.0f);
    float q = 0.f;
#pragma unroll
    for (int t = 0; t < 8; t++) { float d = va[t] - m; q += d * d; }
#pragma unroll
    for (int o = 32; o > 0; o >>= 1) q += __shfl_xor(q, o);
    float inv = rsqrtf(q * (1.0f / 512.0f) + 1e-5f);
    int cb = lane * 8;
    if (OUTBF) {
        u16* o = (u16*)outv + (size_t)row * 512 + cb;
#pragma unroll
        for (int t = 0; t < 8; t++)
            o[t] = f2bf((va[t] - m) * inv * g[cb + t] + b[cb + t]);
    } else {
        float* o = (float*)outv + (size_t)row * 512 + cb;
#pragma unroll
        for (int t = 0; t < 8; t++)
            o[t] = (va[t] - m) * inv * g[cb + t] + b[cb + t];
    }
}

// ---------- MFMA GEMM 64x64 tile, 2 K-subtiles per barrier (R9) ----------
// R9 theory: BK=32 paid one vmcnt(0)-draining __syncthreads per K-step with only
// ~80cy of COMP cover vs ~200cy L2 latency -> ~120cy exposed x nk. R8 proved
// removing barriers via per-wave chains is WORSE; fix is amortization: process
// TWO BK=32 sub-tiles per phase (4 LDS buffers, identical per-subtile layout,
// no swizzle change). Barriers halve (16->8 @K=512, 64->32 @K=2048); COMP per
// phase doubles (8 MFMA + 8 ds_read/wave ~160cy) covering most load latency.
// LDS 32KB -> 5 blocks/CU unchanged occupancy class.
__global__ __launch_bounds__(256) void mgemm64_k(
    const u16* __restrict__ A, const u16* __restrict__ B, const float* __restrict__ bias,
    const float* __restrict__ add, void* __restrict__ Cv,
    int M, int Nn, int Kk, float coef, int act, int outbf) {
    __shared__ u16 lA[4][2048];
    __shared__ u16 lB[4][2048];
    int tid = threadIdx.x;
    int lane = tid & 63;
    int w = tid >> 6;
    int quad = lane >> 4, rl = lane & 15;
    int wm = (w >> 1) * 32, wn = (w & 1) * 32;
    int m0 = blockIdx.x << 6, n0 = blockIdx.y << 6;

    f32x4 acc[2][2];
#pragma unroll
    for (int i = 0; i < 2; i++)
#pragma unroll
        for (int j = 0; j < 2; j++) acc[i][j] = (f32x4){0.f, 0.f, 0.f, 0.f};

    int srow = tid >> 2;          // 0..63
    int scol = (tid & 3) << 3;    // 0,8,16,24
    const u16* gA = A + (size_t)(m0 + srow) * Kk + scol;
    const u16* gB = B + (size_t)(n0 + srow) * Kk + scol;
    int lso = tid * 8;
    int lra = wm * 32 + rl * 32 + quad * 8;   // row-stride 32 u16 (64B)
    int lrb = wn * 32 + rl * 32 + quad * 8;

    auto STAGE2 = [&](int p, int k0) {
#pragma unroll
        for (int s = 0; s < 2; s++) {
            __builtin_amdgcn_global_load_lds(
                (const __attribute__((address_space(1))) void*)(gA + k0 + (s << 5)),
                (__attribute__((address_space(3))) void*)(lA[(p << 1) + s] + lso), 16, 0, 0);
            __builtin_amdgcn_global_load_lds(
                (const __attribute__((address_space(1))) void*)(gB + k0 + (s << 5)),
                (__attribute__((address_space(3))) void*)(lB[(p << 1) + s] + lso), 16, 0, 0);
        }
    };
    auto COMP2 = [&](int p) {
#pragma unroll
        for (int s = 0; s < 2; s++) {
            bf16x8 af[2], bf[2];
#pragma unroll
            for (int t = 0; t < 2; t++) {
                af[t] = *(const bf16x8*)(lA[(p << 1) + s] + lra + t * 512);
                bf[t] = *(const bf16x8*)(lB[(p << 1) + s] + lrb + t * 512);
            }
#pragma unroll
            for (int i = 0; i < 2; i++)
#pragma unroll
                for (int j = 0; j < 2; j++)
                    acc[i][j] = __builtin_amdgcn_mfma_f32_16x16x32_bf16(af[i], bf[j], acc[i][j], 0, 0, 0);
        }
    };

    int nk2 = Kk >> 6;   // K divisible by 64 for all call sites (512/2048)
    STAGE2(0, 0);
    __syncthreads();
    for (int kt = 1; kt < nk2; kt++) {
        STAGE2(kt & 1, kt << 6);
        COMP2((kt - 1) & 1);
        __syncthreads();
    }
    COMP2((nk2 - 1) & 1);

    int rbase = quad * 4;
#pragma unroll
    for (int i = 0; i < 2; i++) {
#pragma unroll
        for (int j = 0; j < 2; j++) {
            int n = n0 + wn + j * 16 + rl;
            float bv = bias ? bias[n] : 0.f;
#pragma unroll
            for (int r = 0; r < 4; r++) {
                int m = m0 + wm + i * 16 + rbase + r;
                float c = acc[i][j][r] + bv;
                if (act == 1) c *= sigm(c);
                size_t o = (size_t)m * Nn + n;
                if (add) c = add[o] + coef * c;
                if (outbf) ((u16*)Cv)[o] = f2bf(c);
                else ((float*)Cv)[o] = c;
            }
        }
    }
}

// ---------- pw1 GEMM with fused GLU epilogue, 2 K-subtiles per barrier (R9) ----------
__global__ __launch_bounds__(256) void mgemmglu_k(
    const u16* __restrict__ A, const u16* __restrict__ B, const float* __restrict__ bias,
    u16* __restrict__ Cv, int Kk) {
    __shared__ u16 lA[4][2048];
    __shared__ u16 lBa[4][2048];
    __shared__ u16 lBg[4][2048];
    int tid = threadIdx.x;
    int lane = tid & 63;
    int w = tid >> 6;
    int quad = lane >> 4, rl = lane & 15;
    int wm = (w >> 1) * 32, wn = (w & 1) * 32;
    int m0 = blockIdx.x << 6, n0 = blockIdx.y << 6;

    f32x4 accA[2][2], accG[2][2];
#pragma unroll
    for (int i = 0; i < 2; i++)
#pragma unroll
        for (int j = 0; j < 2; j++) {
            accA[i][j] = (f32x4){0.f, 0.f, 0.f, 0.f};
            accG[i][j] = (f32x4){0.f, 0.f, 0.f, 0.f};
        }

    int srow = tid >> 2;
    int scol = (tid & 3) << 3;
    const u16* gA  = A + (size_t)(m0 + srow) * Kk + scol;
    const u16* gBa = B + (size_t)(n0 + srow) * Kk + scol;
    const u16* gBg = B + (size_t)(512 + n0 + srow) * Kk + scol;
    int lso = tid * 8;
    int lra = wm * 32 + rl * 32 + quad * 8;
    int lrb = wn * 32 + rl * 32 + quad * 8;

    auto STAGE2 = [&](int p, int k0) {
#pragma unroll
        for (int s = 0; s < 2; s++) {
            __builtin_amdgcn_global_load_lds(
                (const __attribute__((address_space(1))) void*)(gA + k0 + (s << 5)),
                (__attribute__((address_space(3))) void*)(lA[(p << 1) + s] + lso), 16, 0, 0);
            __builtin_amdgcn_global_load_lds(
                (const __attribute__((address_space(1))) void*)(gBa + k0 + (s << 5)),
                (__attribute__((address_space(3))) void*)(lBa[(p << 1) + s] + lso), 16, 0, 0);
            __builtin_amdgcn_global_load_lds(
                (const __attribute__((address_space(1))) void*)(gBg + k0 + (s << 5)),
                (__attribute__((address_space(3))) void*)(lBg[(p << 1) + s] + lso), 16, 0, 0);
        }
    };
    auto COMP2 = [&](int p) {
#pragma unroll
        for (int s = 0; s < 2; s++) {
            bf16x8 af[2], ba[2], bg[2];
#pragma unroll
            for (int t = 0; t < 2; t++) {
                af[t] = *(const bf16x8*)(lA[(p << 1) + s] + lra + t * 512);
                ba[t] = *(const bf16x8*)(lBa[(p << 1) + s] + lrb + t * 512);
                bg[t] = *(const bf16x8*)(lBg[(p << 1) + s] + lrb + t * 512);
            }
#pragma unroll
            for (int i = 0; i < 2; i++)
#pragma unroll
                for (int j = 0; j < 2; j++) {
                    accA[i][j] = __builtin_amdgcn_mfma_f32_16x16x32_bf16(af[i], ba[j], accA[i][j], 0, 0, 0);
                    accG[i][j] = __builtin_amdgcn_mfma_f32_16x16x32_bf16(af[i], bg[j], accG[i][j], 0, 0, 0);
                }
        }
    };

    int nk2 = Kk >> 6;
    STAGE2(0, 0);
    __syncthreads();
    for (int kt = 1; kt < nk2; kt++) {
        STAGE2(kt & 1, kt << 6);
        COMP2((kt - 1) & 1);
        __syncthreads();
    }
    COMP2((nk2 - 1) & 1);

    int rbase = quad * 4;
#pragma unroll
    for (int i = 0; i < 2; i++) {
#pragma unroll
        for (int j = 0; j < 2; j++) {
            int n = n0 + wn + j * 16 + rl;
            float bva = bias[n], bvg = bias[512 + n];
#pragma unroll
            for (int r = 0; r < 4; r++) {
                int m = m0 + wm + i * 16 + rbase + r;
                float a = accA[i][j][r] + bva;
                float g = accG[i][j][r] + bvg;
                Cv[(size_t)m * 512 + n] = f2bf(a * sigm(g));
            }
        }
    }
}

// ---------- pos GEMM 64x64 (R8): Pbf[h][m][d] = pos_emb(1023x512) @ pos_w^T ----------
__global__ __launch_bounds__(256) void posb64_k(const u16* __restrict__ A,
                                                const u16* __restrict__ B,
                                                u16* __restrict__ Pbf) {
    __shared__ u16 lA[2][2048];
    __shared__ u16 lB[2][2048];
    const int Kk = 512;
    int tid = threadIdx.x;
    int lane = tid & 63;
    int w = tid >> 6;
    int quad = lane >> 4, rl = lane & 15;
    int wm = (w >> 1) * 32, wn = (w & 1) * 32;
    int m0 = blockIdx.x << 6, n0 = blockIdx.y << 6;

    f32x4 acc[2][2];
#pragma unroll
    for (int i = 0; i < 2; i++)
#pragma unroll
        for (int j = 0; j < 2; j++) acc[i][j] = (f32x4){0.f, 0.f, 0.f, 0.f};

    int srow = tid >> 2;
    int scol = (tid & 3) << 3;
    int ar = m0 + srow; if (ar > 1022) ar = 1022;
    const u16* gA = A + (size_t)ar * Kk + scol;
    const u16* gB = B + (size_t)(n0 + srow) * Kk + scol;
    int lso = tid * 8;
    int lra = wm * 32 + rl * 32 + quad * 8;
    int lrb = wn * 32 + rl * 32 + quad * 8;

    auto STAGE = [&](int buf, int k0) {
        __builtin_amdgcn_global_load_lds(
            (const __attribute__((address_space(1))) void*)(gA + k0),
            (__attribute__((address_space(3))) void*)(lA[buf] + lso), 16, 0, 0);
        __builtin_amdgcn_global_load_lds(
            (const __attribute__((address_space(1))) void*)(gB + k0),
            (__attribute__((address_space(3))) void*)(lB[buf] + lso), 16, 0, 0);
    };
    auto COMP = [&](int buf) {
        bf16x8 af[2], bf[2];
#pragma unroll
        for (int t = 0; t < 2; t++) {
            af[t] = *(const bf16x8*)(lA[buf] + lra + t * 512);
            bf[t] = *(const bf16x8*)(lB[buf] + lrb + t * 512);
        }
#pragma unroll
        for (int i = 0; i < 2; i++)
#pragma unroll
            for (int j = 0; j < 2; j++)
                acc[i][j] = __builtin_amdgcn_mfma_f32_16x16x32_bf16(af[i], bf[j], acc[i][j], 0, 0, 0);
    };

    int nk = Kk >> 5;
    STAGE(0, 0);
    __syncthreads();
    for (int kt = 1; kt < nk; kt++) {
        STAGE(kt & 1, kt << 5);
        COMP((kt - 1) & 1);
        __syncthreads();
    }
    COMP((nk - 1) & 1);

    int rbase = quad * 4;
#pragma unroll
    for (int i = 0; i < 2; i++) {
#pragma unroll
        for (int j = 0; j < 2; j++) {
            int n = n0 + wn + j * 16 + rl;
            int h = n >> 6, d = n & 63;
#pragma unroll
            for (int r = 0; r < 4; r++) {
                int m = m0 + wm + i * 16 + rbase + r;
                u16 val = (m < 1023) ? f2bf(acc[i][j][r]) : (u16)0;
                Pbf[(((size_t)(h * 1024 + m)) << 6) + d] = val;
            }
        }
    }
}

// ---------- fused flash attention v2 (best measured) ----------
__global__ __launch_bounds__(256) void fattn_k(
    const u16* __restrict__ QU, const u16* __restrict__ QV,
    const u16* __restrict__ Kb, const u16* __restrict__ Pbf,
    const u16* __restrict__ VT, u16* __restrict__ ctx) {
    __shared__ u16 arr[19072];            // 38,144 B -> 4 blocks/CU by LDS
    u16* sRect = arr;                     // bd shifted: 32 rows x stride 524 (scalar acc)
    u16* sP = arr;                        // alias: probs 32 x stride 520 (b128 reads)
    u16* sCtx = arr + 16768;              // 32 x 64 (disjoint from sP)
    float* sRed = (float*)(arr + 18816);  // 32 x 4 floats

    int tid = threadIdx.x;
    int lane = tid & 63, w = tid >> 6;
    int quad = lane >> 4, col = lane & 15;
    int nh = blockIdx.x, h = nh & 7, nb = nh >> 3;
    int m0 = blockIdx.y << 5;             // 32 q-rows per block
    int nlo = 480 - m0;                   // P window: rows nlo..nlo+543 (<=1023)

    const u16* QVz = QV + ((size_t)nh << 15);
    const u16* QUz = QU + ((size_t)nh << 15);
    const u16* Kz  = Kb + ((size_t)nh << 15);
    const u16* Vz  = VT + ((size_t)nh << 15);
    const u16* Pb  = Pbf + ((size_t)h << 16);

    // ---- phase 1: bd(32x544) = QV_tile . P^T, per-tile accumulators retired to sRect ----
    bf16x8 av[2][2];
#pragma unroll
    for (int ks = 0; ks < 2; ks++)
#pragma unroll
        for (int t = 0; t < 2; t++)
            av[ks][t] = *(const bf16x8*)(QVz + ((size_t)(m0 + t * 16 + col) << 6) + (ks << 5) + quad * 8);
#pragma unroll
    for (int idx = 0; idx < 9; idx++) {
        int nt = w + (idx << 2);
        if (nt < 34) {
            int crow = nt * 16 + col;
            const u16* pb = Pb + ((size_t)(nlo + crow) << 6) + quad * 8;
            f32x4 b0 = (f32x4){0.f, 0.f, 0.f, 0.f};
            f32x4 b1 = (f32x4){0.f, 0.f, 0.f, 0.f};
#pragma unroll
            for (int ks = 0; ks < 2; ks++) {
                bf16x8 bfr = *(const bf16x8*)(pb + (ks << 5));
                b0 = __builtin_amdgcn_mfma_f32_16x16x32_bf16(av[ks][0], bfr, b0, 0, 0, 0);
                b1 = __builtin_amdgcn_mfma_f32_16x16x32_bf16(av[ks][1], bfr, b1, 0, 0, 0);
            }
            // shifted write: rect col c -> j = c + ml - 31; stride 524
#pragma unroll
            for (int r = 0; r < 4; r++) {
                int ml0 = quad * 4 + r;
                int j0 = crow + ml0 - 31;
                if (j0 >= 0 && j0 < 512) sRect[ml0 * 524 + j0] = f2bf(b0[r]);
                int ml1 = ml0 + 16;
                int j1 = crow + ml1 - 31;
                if (j1 >= 0 && j1 < 512) sRect[ml1 * 524 + j1] = f2bf(b1[r]);
            }
        }
    }

    // ---- phase 2: ac(32x512) = QU_tile . K^T (direct reads, no barriers) ----
    bf16x8 au[2][2];
#pragma unroll
    for (int ks = 0; ks < 2; ks++)
#pragma unroll
        for (int t = 0; t < 2; t++)
            au[ks][t] = *(const bf16x8*)(QUz + ((size_t)(m0 + t * 16 + col) << 6) + (ks << 5) + quad * 8);
    f32x4 ac[2][8];
#pragma unroll
    for (int t = 0; t < 2; t++)
#pragma unroll
        for (int jt = 0; jt < 8; jt++) ac[t][jt] = (f32x4){0.f, 0.f, 0.f, 0.f};
#pragma unroll
    for (int jt = 0; jt < 8; jt++) {
        const u16* kp = Kz + ((size_t)((w << 7) + jt * 16 + col) << 6) + quad * 8;
#pragma unroll
        for (int ks = 0; ks < 2; ks++) {
            bf16x8 bfr = *(const bf16x8*)(kp + (ks << 5));
            ac[0][jt] = __builtin_amdgcn_mfma_f32_16x16x32_bf16(au[ks][0], bfr, ac[0][jt], 0, 0, 0);
            ac[1][jt] = __builtin_amdgcn_mfma_f32_16x16x32_bf16(au[ks][1], bfr, ac[1][jt], 0, 0, 0);
        }
    }
    __syncthreads();  // all sRect writes visible before phase-3 reads

    // ---- phase 3: shifted add + scale + softmax over j ----
    float rmax[2][4];
#pragma unroll
    for (int t = 0; t < 2; t++)
#pragma unroll
        for (int r = 0; r < 4; r++) rmax[t][r] = -1e30f;
#pragma unroll
    for (int jt = 0; jt < 8; jt++) {
        int j = (w << 7) + jt * 16 + col;
#pragma unroll
        for (int t = 0; t < 2; t++)
#pragma unroll
            for (int r = 0; r < 4; r++) {
                int ml = t * 16 + quad * 4 + r;
                float v = (ac[t][jt][r] + bf2f(sRect[ml * 524 + j])) * 0.125f;
                ac[t][jt][r] = v;
                rmax[t][r] = fmaxf(rmax[t][r], v);
            }
    }
#pragma unroll
    for (int o = 1; o <= 8; o <<= 1)
#pragma unroll
        for (int t = 0; t < 2; t++)
#pragma unroll
            for (int r = 0; r < 4; r++) rmax[t][r] = fmaxf(rmax[t][r], __shfl_xor(rmax[t][r], o));
    if (col == 0)
#pragma unroll
        for (int t = 0; t < 2; t++)
#pragma unroll
            for (int r = 0; r < 4; r++) sRed[(t * 16 + quad * 4 + r) * 4 + w] = rmax[t][r];
    __syncthreads();
    float gmax[2][4], psum[2][4];
#pragma unroll
    for (int t = 0; t < 2; t++)
#pragma unroll
        for (int r = 0; r < 4; r++) {
            int ml = t * 16 + quad * 4 + r;
            gmax[t][r] = fmaxf(fmaxf(sRed[ml * 4 + 0], sRed[ml * 4 + 1]),
                               fmaxf(sRed[ml * 4 + 2], sRed[ml * 4 + 3]));
            psum[t][r] = 0.f;
        }
    __syncthreads();
#pragma unroll
    for (int jt = 0; jt < 8; jt++)
#pragma unroll
        for (int t = 0; t < 2; t++)
#pragma unroll
            for (int r = 0; r < 4; r++) {
                float e = __expf(ac[t][jt][r] - gmax[t][r]);
                ac[t][jt][r] = e;
                psum[t][r] += e;
            }
#pragma unroll
    for (int o = 1; o <= 8; o <<= 1)
#pragma unroll
        for (int t = 0; t < 2; t++)
#pragma unroll
            for (int r = 0; r < 4; r++) psum[t][r] += __shfl_xor(psum[t][r], o);
    if (col == 0)
#pragma unroll
        for (int t = 0; t < 2; t++)
#pragma unroll
            for (int r = 0; r < 4; r++) sRed[(t * 16 + quad * 4 + r) * 4 + w] = psum[t][r];
    __syncthreads();
    float rinv[2][4];
#pragma unroll
    for (int t = 0; t < 2; t++)
#pragma unroll
        for (int r = 0; r < 4; r++) {
            int ml = t * 16 + quad * 4 + r;
            rinv[t][r] = 1.f / (sRed[ml * 4 + 0] + sRed[ml * 4 + 1] + sRed[ml * 4 + 2] + sRed[ml * 4 + 3]);
        }

    // ---- phase 4: probs -> sP (stride 520; sRect reads are >=2 barriers past) ----
#pragma unroll
    for (int jt = 0; jt < 8; jt++) {
        int j = (w << 7) + jt * 16 + col;
#pragma unroll
        for (int t = 0; t < 2; t++)
#pragma unroll
            for (int r = 0; r < 4; r++)
                sP[(t * 16 + quad * 4 + r) * 520 + j] = f2bf(ac[t][jt][r] * rinv[t][r]);
    }
    __syncthreads();

    // ---- phase 5: ctx(32x64) = P(32x512) . V^T, V fragments direct from L2 ----
    f32x4 cacc[2];
    cacc[0] = (f32x4){0.f, 0.f, 0.f, 0.f};
    cacc[1] = (f32x4){0.f, 0.f, 0.f, 0.f};
    {
        const u16* vp = Vz + ((size_t)((w << 4) + col) << 9) + quad * 8;
#pragma unroll
        for (int kc = 0; kc < 2; kc++)
#pragma unroll
            for (int s2 = 0; s2 < 8; s2++) {
                int ko = (kc << 8) + (s2 << 5);
                bf16x8 a0 = *(const bf16x8*)(sP + col * 520 + ko + quad * 8);
                bf16x8 a1 = *(const bf16x8*)(sP + (col + 16) * 520 + ko + quad * 8);
                bf16x8 bfr = *(const bf16x8*)(vp + ko);
                cacc[0] = __builtin_amdgcn_mfma_f32_16x16x32_bf16(a0, bfr, cacc[0], 0, 0, 0);
                cacc[1] = __builtin_amdgcn_mfma_f32_16x16x32_bf16(a1, bfr, cacc[1], 0, 0, 0);
            }
    }

    // ---- phase 6: ctx tile -> LDS (disjoint region) -> coalesced 16B stores ----
#pragma unroll
    for (int t = 0; t < 2; t++)
#pragma unroll
        for (int r = 0; r < 4; r++)
            sCtx[(t * 16 + quad * 4 + r) * 64 + (w << 4) + col] = f2bf(cacc[t][r]);
    __syncthreads();
    {
        int row = tid >> 3, seg = tid & 7;
        u16* dst = ctx + (((size_t)((m0 + row) * 16 + nb)) << 9) + (h << 6) + seg * 8;
        *(uint4*)dst = *(const uint4*)(sCtx + row * 64 + seg * 8);
    }
}

// ---------- repack qkv: vectorized, VT via LDS transpose (coalesced writes) ----------
__global__ __launch_bounds__(256) void repack_k(const u16* __restrict__ qkv,
                                                const float* __restrict__ bu,
                                                const float* __restrict__ bv,
                                                u16* __restrict__ QU, u16* __restrict__ QV,
                                                u16* __restrict__ Kb, u16* __restrict__ VT) {
    __shared__ u16 sV[64 * 72];  // 9216 B, stride 72 (8-aligned, bank step 4)
    int nh = blockIdx.x, h = nh & 7, n = nh >> 3;
    int l0 = blockIdx.y << 6;
    int tid = threadIdx.x;
    int d8 = (tid & 7) << 3;
    float bub[8], bvb[8];
#pragma unroll
    for (int e = 0; e < 8; e++) {
        bub[e] = bu[h * 64 + d8 + e];
        bvb[e] = bv[h * 64 + d8 + e];
    }
#pragma unroll
    for (int rep = 0; rep < 2; rep++) {
        int ll = (tid >> 3) + rep * 32;
        int l = l0 + ll;
        size_t base = (size_t)(l * 16 + n) * 1536 + h * 64 + d8;
        u16x8 q = *(const u16x8*)(qkv + base);
        u16x8 k = *(const u16x8*)(qkv + base + 512);
        u16x8 v = *(const u16x8*)(qkv + base + 1024);
        u16x8 qu, qv;
#pragma unroll
        for (int e = 0; e < 8; e++) {
            float qf = bf2f(q[e]);
            qu[e] = f2bf(qf + bub[e]);
            qv[e] = f2bf(qf + bvb[e]);
        }
        size_t o = ((size_t)nh * 512 + l) * 64 + d8;
        *(u16x8*)(QU + o) = qu;
        *(u16x8*)(QV + o) = qv;
        *(u16x8*)(Kb + o) = k;
        *(u16x8*)(sV + ll * 72 + d8) = v;
    }
    __syncthreads();
    int d = tid >> 2, ls = (tid & 3) << 4;
    u16 tmp[16];
#pragma unroll
    for (int e = 0; e < 16; e++) tmp[e] = sV[(ls + e) * 72 + d];
    u16* dst = VT + ((size_t)nh * 64 + d) * 512 + l0 + ls;
    *(u16x8*)(dst) = *(const u16x8*)(tmp);
    *(u16x8*)(dst + 8) = *(const u16x8*)(tmp + 8);
}

// ---------- depthwise conv: sliding window, 16 outputs per thread ----------
__global__ __launch_bounds__(256) void dwconv_k(
    const u16* __restrict__ g, const float* __restrict__ w, const float* __restrict__ wb,
    const float* __restrict__ bng, const float* __restrict__ bnb, const float* __restrict__ bnm,
    const float* __restrict__ bnv, u16* __restrict__ out) {
    int idx = blockIdx.x * 256 + threadIdx.x;  // 262144 threads
    int c = idx & 511;
    int t = idx >> 9;
    int n = t & 15, l0 = (t >> 4) << 4;
    float win[46];
#pragma unroll
    for (int q = 0; q < 46; q++) {
        int ll = l0 - 15 + q;
        win[q] = (ll >= 0 && ll < 512) ? bf2f(g[((size_t)(ll * 16 + n) << 9) + c]) : 0.f;
    }
    float wgt[31];
#pragma unroll
    for (int k = 0; k < 31; k++) wgt[k] = w[c * 31 + k];
    float ivg = rsqrtf(bnv[c] + 1e-5f) * bng[c];
    float mc = bnm[c], bc = bnb[c], wbc = wb[c];
#pragma unroll
    for (int r = 0; r < 16; r++) {
        float acc = 0.f;
#pragma unroll
        for (int k = 0; k < 31; k++) acc += wgt[k] * win[r + k];
        acc += wbc;
        float y = (acc - mc) * ivg + bc;
        y = y * sigm(y);
        out[((size_t)((l0 + r) * 16 + n) << 9) + c] = f2bf(y);
    }
}

// ---------- launch ----------
extern "C" void kernel_launch(void* const* d_in, const int* in_sizes, int n_in,
                              void* d_out, int out_size, void* d_ws, size_t ws_size,
                              hipStream_t stream) {
    const float* src      = (const float*)d_in[0];
    const float* pos_emb  = (const float*)d_in[1];
    const float* ffm_w1   = (const float*)d_in[2];
    const float* ffm_b1   = (const float*)d_in[3];
    const float* ffm_w2   = (const float*)d_in[4];
    const float* ffm_b2   = (const float*)d_in[5];
    const float* ff_w1    = (const float*)d_in[6];
    const float* ff_b1    = (const float*)d_in[7];
    const float* ff_w2    = (const float*)d_in[8];
    const float* ff_b2    = (const float*)d_in[9];
    const float* in_w     = (const float*)d_in[10];
    const float* in_b     = (const float*)d_in[11];
    const float* out_w    = (const float*)d_in[12];
    const float* out_b    = (const float*)d_in[13];
    const float* pos_w    = (const float*)d_in[14];
    const float* bu       = (const float*)d_in[15];
    const float* bv       = (const float*)d_in[16];
    const float* pw1_w    = (const float*)d_in[17];
    const float* pw1_b    = (const float*)d_in[18];
    const float* dw_w     = (const float*)d_in[19];
    const float* dw_b     = (const float*)d_in[20];
    const float* bng      = (const float*)d_in[21];
    const float* bnb      = (const float*)d_in[22];
    const float* bnm      = (const float*)d_in[23];
    const float* bnv      = (const float*)d_in[24];
    const float* pw2_w    = (const float*)d_in[25];
    const float* pw2_b    = (const float*)d_in[26];
    const float* ln_ffm_g = (const float*)d_in[27];
    const float* ln_ffm_b = (const float*)d_in[28];
    const float* ln_mha_g = (const float*)d_in[29];
    const float* ln_mha_b = (const float*)d_in[30];
    const float* ln_cv_g  = (const float*)d_in[31];
    const float* ln_cv_b  = (const float*)d_in[32];
    const float* ln_ff_g  = (const float*)d_in[33];
    const float* ln_ff_b  = (const float*)d_in[34];
    const float* ln_fin_g = (const float*)d_in[35];
    const float* ln_fin_b = (const float*)d_in[36];
    (void)in_sizes; (void)n_in; (void)out_size; (void)ws_size;

    // ---- workspace layout in u16 units; total ~117 MiB ----
    const size_t MEG = 1048576;
    u16* U = (u16*)d_ws;
    float* xA = (float*)U;                // 8M u16; Pbf aliases during attention
    u16* Pbf = U;                         // 524288 u16 (8 x 1024 x 64)
    float* xB = (float*)(U + 8 * MEG);    // 8M
    u16* LNB = U + 16 * MEG;              // 4M
    u16* BIG = U + 20 * MEG;              // 16M: h1 / qkv
    u16* QU = U + 36 * MEG;               // 4M
    u16* QV = U + 40 * MEG;               // 4M
    u16* Kb = U + 44 * MEG;               // 4M
    u16* VT = U + 48 * MEG;               // 4M
    u16* WB = U + 52 * MEG;               // 6,815,232 weights bf16
    u16* w_ffm1 = WB;
    u16* w_ffm2 = WB + 1 * MEG;
    u16* w_ff1  = WB + 2 * MEG;
    u16* w_ff2  = WB + 3 * MEG;
    u16* w_in   = WB + 4 * MEG;
    u16* w_out  = WB + 4 * MEG + 786432;
    u16* w_pw1  = WB + 5 * MEG;
    u16* w_pw2  = WB + 5 * MEG + 524288;
    u16* w_pos  = WB + 6029312;           // 512x512
    u16* w_pe   = WB + 6291456;           // 1023x512
    u16* CTX = LNB;
    u16* GLU = QU;
    u16* CACT = QV;

    // ---- cast all weights + pos inputs to bf16 (one dispatch, float4) ----
    castall_k<<<6656, 256, 0, stream>>>(ffm_w1, ffm_w2, ff_w1, ff_w2, in_w, out_w,
                                        pw1_w, pw2_w, pos_w, pos_emb, WB);

    // ---- FFN macaron: xB = src + 0.5*ffn(ln(src)) ----
    ln512_k<true><<<2048, 256, 0, stream>>>(src, ln_ffm_g, ln_ffm_b, LNB);
    mgemm64_k<<<dim3(128, 32), 256, 0, stream>>>(LNB, w_ffm1, ffm_b1, nullptr, BIG,
                                                 8192, 2048, 512, 0.f, 1, 1);
    mgemm64_k<<<dim3(128, 8), 256, 0, stream>>>(BIG, w_ffm2, ffm_b2, src, xB,
                                                8192, 512, 2048, 0.5f, 0, 0);

    // ---- attention: xA = xB + attn(ln(xB)) ----
    ln512_k<true><<<2048, 256, 0, stream>>>(xB, ln_mha_g, ln_mha_b, LNB);
    posb64_k<<<dim3(16, 8), 256, 0, stream>>>(w_pe, w_pos, Pbf);
    mgemm64_k<<<dim3(128, 24), 256, 0, stream>>>(LNB, w_in, in_b, nullptr, BIG,
                                                 8192, 1536, 512, 0.f, 0, 1);
    repack_k<<<dim3(128, 8), 256, 0, stream>>>(BIG, bu, bv, QU, QV, Kb, VT);
    fattn_k<<<dim3(128, 16), 256, 0, stream>>>(QU, QV, Kb, Pbf, VT, CTX);
    mgemm64_k<<<dim3(128, 8), 256, 0, stream>>>(CTX, w_out, out_b, xB, xA,
                                                8192, 512, 512, 1.f, 0, 0);

    // ---- conv module: xB = xA + conv(ln(xA)) ----
    ln512_k<true><<<2048, 256, 0, stream>>>(xA, ln_cv_g, ln_cv_b, LNB);
    mgemmglu_k<<<dim3(128, 8), 256, 0, stream>>>(LNB, w_pw1, pw1_b, GLU, 512);
    dwconv_k<<<1024, 256, 0, stream>>>(GLU, dw_w, dw_b, bng, bnb, bnm, bnv, CACT);
    mgemm64_k<<<dim3(128, 8), 256, 0, stream>>>(CACT, w_pw2, pw2_b, xA, xB,
                                                8192, 512, 512, 1.f, 0, 0);

    // ---- FFN 2: xA = xB + 0.5*ffn(ln(xB)) ----
    ln512_k<true><<<2048, 256, 0, stream>>>(xB, ln_ff_g, ln_ff_b, LNB);
    mgemm64_k<<<dim3(128, 32), 256, 0, stream>>>(LNB, w_ff1, ff_b1, nullptr, BIG,
                                                 8192, 2048, 512, 0.f, 1, 1);
    mgemm64_k<<<dim3(128, 8), 256, 0, stream>>>(BIG, w_ff2, ff_b2, xB, xA,
                                                8192, 512, 2048, 0.5f, 0, 0);

    // ---- final LN -> fp32 out ----
    ln512_k<false><<<2048, 256, 0, stream>>>(xA, ln_fin_g, ln_fin_b, (float*)d_out);
}

// Round 11
// 503.861 us; speedup vs baseline: 1.2660x; 1.0086x over previous
//
#include <hip/hip_runtime.h>
#include <cstdint>
#include <cstddef>

typedef unsigned short u16;
typedef __attribute__((ext_vector_type(4))) float f32x4;
typedef __attribute__((ext_vector_type(8))) short bf16x8;
typedef __attribute__((ext_vector_type(8))) unsigned short u16x8;

// ---------- helpers ----------
__device__ __forceinline__ float sigm(float x) { return 1.f / (1.f + __expf(-x)); }
__device__ __forceinline__ float bf2f(u16 u) {
    union { unsigned int i; float f; } c; c.i = ((unsigned int)u) << 16; return c.f;
}
__device__ __forceinline__ u16 f2bf(float f) {
    union { float f; unsigned int i; } c; c.f = f;
    unsigned int x = c.i;
    x += 0x7fffu + ((x >> 16) & 1u);
    return (u16)(x >> 16);
}

// dims: D=512, H=8, DH=64, F=2048, K=31, L=512, N=16, M=8192

// ---------- fused prologue (R10): weight-cast (blocks 0..6655) + first LN (6656..8703) ----------
// castall and ln_ffm are independent (WB vs LNB) -> one dispatch, no half-empty tail.
__global__ __launch_bounds__(256) void fusedpre_k(
    const float* __restrict__ s0, const float* __restrict__ s1,
    const float* __restrict__ s2, const float* __restrict__ s3,
    const float* __restrict__ s4, const float* __restrict__ s5,
    const float* __restrict__ s6, const float* __restrict__ s7,
    const float* __restrict__ s8, const float* __restrict__ s9,
    u16* __restrict__ dst,
    const float* __restrict__ x, const float* __restrict__ g,
    const float* __restrict__ b, u16* __restrict__ lnout) {
    if (blockIdx.x < 6656) {
        int i = (blockIdx.x * 256 + threadIdx.x) << 2;
        if (i >= 6815232) return;
        const float* s; int off;
        if      (i < 1048576) { s = s0; off = 0; }
        else if (i < 2097152) { s = s1; off = 1048576; }
        else if (i < 3145728) { s = s2; off = 2097152; }
        else if (i < 4194304) { s = s3; off = 3145728; }
        else if (i < 4980736) { s = s4; off = 4194304; }
        else if (i < 5242880) { s = s5; off = 4980736; }
        else if (i < 5767168) { s = s6; off = 5242880; }
        else if (i < 6029312) { s = s7; off = 5767168; }
        else if (i < 6291456) { s = s8; off = 6029312; }
        else                  { s = s9; off = 6291456; }
        float4 v = *(const float4*)(s + (i - off));
        union { unsigned int u[2]; } o;
        o.u[0] = (unsigned int)f2bf(v.x) | ((unsigned int)f2bf(v.y) << 16);
        o.u[1] = (unsigned int)f2bf(v.z) | ((unsigned int)f2bf(v.w) << 16);
        *(uint2*)(dst + i) = *(const uint2*)o.u;
    } else {
        int row = (blockIdx.x - 6656) * 4 + (threadIdx.x >> 6);
        int lane = threadIdx.x & 63;
        const float* xr = x + (size_t)row * 512 + lane * 8;
        float4 v0 = *(const float4*)(xr);
        float4 v1 = *(const float4*)(xr + 4);
        float va[8] = {v0.x, v0.y, v0.z, v0.w, v1.x, v1.y, v1.z, v1.w};
        float s = 0.f;
#pragma unroll
        for (int t = 0; t < 8; t++) s += va[t];
#pragma unroll
        for (int o = 32; o > 0; o >>= 1) s += __shfl_xor(s, o);
        float m = s * (1.0f / 512.0f);
        float q = 0.f;
#pragma unroll
        for (int t = 0; t < 8; t++) { float d = va[t] - m; q += d * d; }
#pragma unroll
        for (int o = 32; o > 0; o >>= 1) q += __shfl_xor(q, o);
        float inv = rsqrtf(q * (1.0f / 512.0f) + 1e-5f);
        int cb = lane * 8;
        u16* o = lnout + (size_t)row * 512 + cb;
#pragma unroll
        for (int t = 0; t < 8; t++)
            o[t] = f2bf((va[t] - m) * inv * g[cb + t] + b[cb + t]);
    }
}

// ---------- LayerNorm over 512 (fp32 in), 4 rows per 256-thread block ----------
template <bool OUTBF>
__global__ __launch_bounds__(256) void ln512_k(const float* __restrict__ x,
                                               const float* __restrict__ g,
                                               const float* __restrict__ b,
                                               void* __restrict__ outv) {
    int row = blockIdx.x * 4 + (threadIdx.x >> 6);
    int lane = threadIdx.x & 63;
    const float* xr = x + (size_t)row * 512 + lane * 8;
    float4 v0 = *(const float4*)(xr);
    float4 v1 = *(const float4*)(xr + 4);
    float va[8] = {v0.x, v0.y, v0.z, v0.w, v1.x, v1.y, v1.z, v1.w};
    float s = 0.f;
#pragma unroll
    for (int t = 0; t < 8; t++) s += va[t];
#pragma unroll
    for (int o = 32; o > 0; o >>= 1) s += __shfl_xor(s, o);
    float m = s * (1.0f / 512.0f);
    float q = 0.f;
#pragma unroll
    for (int t = 0; t < 8; t++) { float d = va[t] - m; q += d * d; }
#pragma unroll
    for (int o = 32; o > 0; o >>= 1) q += __shfl_xor(q, o);
    float inv = rsqrtf(q * (1.0f / 512.0f) + 1e-5f);
    int cb = lane * 8;
    if (OUTBF) {
        u16* o = (u16*)outv + (size_t)row * 512 + cb;
#pragma unroll
        for (int t = 0; t < 8; t++)
            o[t] = f2bf((va[t] - m) * inv * g[cb + t] + b[cb + t]);
    } else {
        float* o = (float*)outv + (size_t)row * 512 + cb;
#pragma unroll
        for (int t = 0; t < 8; t++)
            o[t] = (va[t] - m) * inv * g[cb + t] + b[cb + t];
    }
}

// ---------- MFMA GEMM 64x64 tile, 2 K-subtiles per barrier (R9) ----------
__global__ __launch_bounds__(256) void mgemm64_k(
    const u16* __restrict__ A, const u16* __restrict__ B, const float* __restrict__ bias,
    const float* __restrict__ add, void* __restrict__ Cv,
    int M, int Nn, int Kk, float coef, int act, int outbf) {
    __shared__ u16 lA[4][2048];
    __shared__ u16 lB[4][2048];
    int tid = threadIdx.x;
    int lane = tid & 63;
    int w = tid >> 6;
    int quad = lane >> 4, rl = lane & 15;
    int wm = (w >> 1) * 32, wn = (w & 1) * 32;
    int m0 = blockIdx.x << 6, n0 = blockIdx.y << 6;

    f32x4 acc[2][2];
#pragma unroll
    for (int i = 0; i < 2; i++)
#pragma unroll
        for (int j = 0; j < 2; j++) acc[i][j] = (f32x4){0.f, 0.f, 0.f, 0.f};

    int srow = tid >> 2;          // 0..63
    int scol = (tid & 3) << 3;    // 0,8,16,24
    const u16* gA = A + (size_t)(m0 + srow) * Kk + scol;
    const u16* gB = B + (size_t)(n0 + srow) * Kk + scol;
    int lso = tid * 8;
    int lra = wm * 32 + rl * 32 + quad * 8;   // row-stride 32 u16 (64B)
    int lrb = wn * 32 + rl * 32 + quad * 8;

    auto STAGE2 = [&](int p, int k0) {
#pragma unroll
        for (int s = 0; s < 2; s++) {
            __builtin_amdgcn_global_load_lds(
                (const __attribute__((address_space(1))) void*)(gA + k0 + (s << 5)),
                (__attribute__((address_space(3))) void*)(lA[(p << 1) + s] + lso), 16, 0, 0);
            __builtin_amdgcn_global_load_lds(
                (const __attribute__((address_space(1))) void*)(gB + k0 + (s << 5)),
                (__attribute__((address_space(3))) void*)(lB[(p << 1) + s] + lso), 16, 0, 0);
        }
    };
    auto COMP2 = [&](int p) {
#pragma unroll
        for (int s = 0; s < 2; s++) {
            bf16x8 af[2], bf[2];
#pragma unroll
            for (int t = 0; t < 2; t++) {
                af[t] = *(const bf16x8*)(lA[(p << 1) + s] + lra + t * 512);
                bf[t] = *(const bf16x8*)(lB[(p << 1) + s] + lrb + t * 512);
            }
#pragma unroll
            for (int i = 0; i < 2; i++)
#pragma unroll
                for (int j = 0; j < 2; j++)
                    acc[i][j] = __builtin_amdgcn_mfma_f32_16x16x32_bf16(af[i], bf[j], acc[i][j], 0, 0, 0);
        }
    };

    int nk2 = Kk >> 6;   // K divisible by 64 for all call sites (512/2048)
    STAGE2(0, 0);
    __syncthreads();
    for (int kt = 1; kt < nk2; kt++) {
        STAGE2(kt & 1, kt << 6);
        COMP2((kt - 1) & 1);
        __syncthreads();
    }
    COMP2((nk2 - 1) & 1);

    int rbase = quad * 4;
#pragma unroll
    for (int i = 0; i < 2; i++) {
#pragma unroll
        for (int j = 0; j < 2; j++) {
            int n = n0 + wn + j * 16 + rl;
            float bv = bias ? bias[n] : 0.f;
#pragma unroll
            for (int r = 0; r < 4; r++) {
                int m = m0 + wm + i * 16 + rbase + r;
                float c = acc[i][j][r] + bv;
                if (act == 1) c *= sigm(c);
                size_t o = (size_t)m * Nn + n;
                if (add) c = add[o] + coef * c;
                if (outbf) ((u16*)Cv)[o] = f2bf(c);
                else ((float*)Cv)[o] = c;
            }
        }
    }
}

// ---------- fused in-proj GEMM + pos GEMM (R10): grid (128, 25) ----------
// y<24: qkv = ln(xB) @ in_w^T + in_b (M=8192, N=1536, K=512, bf16 out)
// y==24: Pbf = pos_emb(1023x512, row-clamped) @ pos_w^T (h-major remap; m=1023 -> 0)
// Independent outputs; merging removes a half-empty 128-block dispatch.
__global__ __launch_bounds__(256) void qkvpos_k(
    const u16* __restrict__ A, const u16* __restrict__ B, const float* __restrict__ bias,
    u16* __restrict__ C, const u16* __restrict__ pA, const u16* __restrict__ pB,
    u16* __restrict__ Pbf) {
    __shared__ u16 lA[4][2048];
    __shared__ u16 lB[4][2048];
    const int Kk = 512;
    int tid = threadIdx.x;
    int lane = tid & 63;
    int w = tid >> 6;
    int quad = lane >> 4, rl = lane & 15;
    int wm = (w >> 1) * 32, wn = (w & 1) * 32;
    int srow = tid >> 2;
    int scol = (tid & 3) << 3;
    int lso = tid * 8;
    int lra = wm * 32 + rl * 32 + quad * 8;
    int lrb = wn * 32 + rl * 32 + quad * 8;

    f32x4 acc[2][2];
#pragma unroll
    for (int i = 0; i < 2; i++)
#pragma unroll
        for (int j = 0; j < 2; j++) acc[i][j] = (f32x4){0.f, 0.f, 0.f, 0.f};

    bool ispos = (blockIdx.y == 24);
    int m0, n0;
    const u16 *gA, *gB;
    if (!ispos) {
        m0 = blockIdx.x << 6; n0 = blockIdx.y << 6;
        gA = A + (size_t)(m0 + srow) * Kk + scol;
        gB = B + (size_t)(n0 + srow) * Kk + scol;
    } else {
        int bx = blockIdx.x;
        m0 = (bx >> 3) << 6; n0 = (bx & 7) << 6;
        int ar = m0 + srow; if (ar > 1022) ar = 1022;
        gA = pA + (size_t)ar * Kk + scol;
        gB = pB + (size_t)(n0 + srow) * Kk + scol;
    }

    auto STAGE2 = [&](int p, int k0) {
#pragma unroll
        for (int s = 0; s < 2; s++) {
            __builtin_amdgcn_global_load_lds(
                (const __attribute__((address_space(1))) void*)(gA + k0 + (s << 5)),
                (__attribute__((address_space(3))) void*)(lA[(p << 1) + s] + lso), 16, 0, 0);
            __builtin_amdgcn_global_load_lds(
                (const __attribute__((address_space(1))) void*)(gB + k0 + (s << 5)),
                (__attribute__((address_space(3))) void*)(lB[(p << 1) + s] + lso), 16, 0, 0);
        }
    };
    auto COMP2 = [&](int p) {
#pragma unroll
        for (int s = 0; s < 2; s++) {
            bf16x8 af[2], bf[2];
#pragma unroll
            for (int t = 0; t < 2; t++) {
                af[t] = *(const bf16x8*)(lA[(p << 1) + s] + lra + t * 512);
                bf[t] = *(const bf16x8*)(lB[(p << 1) + s] + lrb + t * 512);
            }
#pragma unroll
            for (int i = 0; i < 2; i++)
#pragma unroll
                for (int j = 0; j < 2; j++)
                    acc[i][j] = __builtin_amdgcn_mfma_f32_16x16x32_bf16(af[i], bf[j], acc[i][j], 0, 0, 0);
        }
    };

    const int nk2 = 8;  // K=512
    STAGE2(0, 0);
    __syncthreads();
    for (int kt = 1; kt < nk2; kt++) {
        STAGE2(kt & 1, kt << 6);
        COMP2((kt - 1) & 1);
        __syncthreads();
    }
    COMP2((nk2 - 1) & 1);

    int rbase = quad * 4;
    if (!ispos) {
#pragma unroll
        for (int i = 0; i < 2; i++) {
#pragma unroll
            for (int j = 0; j < 2; j++) {
                int n = n0 + wn + j * 16 + rl;
                float bv = bias[n];
#pragma unroll
                for (int r = 0; r < 4; r++) {
                    int m = m0 + wm + i * 16 + rbase + r;
                    C[(size_t)m * 1536 + n] = f2bf(acc[i][j][r] + bv);
                }
            }
        }
    } else {
#pragma unroll
        for (int i = 0; i < 2; i++) {
#pragma unroll
            for (int j = 0; j < 2; j++) {
                int n = n0 + wn + j * 16 + rl;
                int h = n >> 6, d = n & 63;
#pragma unroll
                for (int r = 0; r < 4; r++) {
                    int m = m0 + wm + i * 16 + rbase + r;
                    u16 val = (m < 1023) ? f2bf(acc[i][j][r]) : (u16)0;
                    Pbf[(((size_t)(h * 1024 + m)) << 6) + d] = val;
                }
            }
        }
    }
}

// ---------- pw1 GEMM with fused GLU epilogue, 2 K-subtiles per barrier (R9) ----------
__global__ __launch_bounds__(256) void mgemmglu_k(
    const u16* __restrict__ A, const u16* __restrict__ B, const float* __restrict__ bias,
    u16* __restrict__ Cv, int Kk) {
    __shared__ u16 lA[4][2048];
    __shared__ u16 lBa[4][2048];
    __shared__ u16 lBg[4][2048];
    int tid = threadIdx.x;
    int lane = tid & 63;
    int w = tid >> 6;
    int quad = lane >> 4, rl = lane & 15;
    int wm = (w >> 1) * 32, wn = (w & 1) * 32;
    int m0 = blockIdx.x << 6, n0 = blockIdx.y << 6;

    f32x4 accA[2][2], accG[2][2];
#pragma unroll
    for (int i = 0; i < 2; i++)
#pragma unroll
        for (int j = 0; j < 2; j++) {
            accA[i][j] = (f32x4){0.f, 0.f, 0.f, 0.f};
            accG[i][j] = (f32x4){0.f, 0.f, 0.f, 0.f};
        }

    int srow = tid >> 2;
    int scol = (tid & 3) << 3;
    const u16* gA  = A + (size_t)(m0 + srow) * Kk + scol;
    const u16* gBa = B + (size_t)(n0 + srow) * Kk + scol;
    const u16* gBg = B + (size_t)(512 + n0 + srow) * Kk + scol;
    int lso = tid * 8;
    int lra = wm * 32 + rl * 32 + quad * 8;
    int lrb = wn * 32 + rl * 32 + quad * 8;

    auto STAGE2 = [&](int p, int k0) {
#pragma unroll
        for (int s = 0; s < 2; s++) {
            __builtin_amdgcn_global_load_lds(
                (const __attribute__((address_space(1))) void*)(gA + k0 + (s << 5)),
                (__attribute__((address_space(3))) void*)(lA[(p << 1) + s] + lso), 16, 0, 0);
            __builtin_amdgcn_global_load_lds(
                (const __attribute__((address_space(1))) void*)(gBa + k0 + (s << 5)),
                (__attribute__((address_space(3))) void*)(lBa[(p << 1) + s] + lso), 16, 0, 0);
            __builtin_amdgcn_global_load_lds(
                (const __attribute__((address_space(1))) void*)(gBg + k0 + (s << 5)),
                (__attribute__((address_space(3))) void*)(lBg[(p << 1) + s] + lso), 16, 0, 0);
        }
    };
    auto COMP2 = [&](int p) {
#pragma unroll
        for (int s = 0; s < 2; s++) {
            bf16x8 af[2], ba[2], bg[2];
#pragma unroll
            for (int t = 0; t < 2; t++) {
                af[t] = *(const bf16x8*)(lA[(p << 1) + s] + lra + t * 512);
                ba[t] = *(const bf16x8*)(lBa[(p << 1) + s] + lrb + t * 512);
                bg[t] = *(const bf16x8*)(lBg[(p << 1) + s] + lrb + t * 512);
            }
#pragma unroll
            for (int i = 0; i < 2; i++)
#pragma unroll
                for (int j = 0; j < 2; j++) {
                    accA[i][j] = __builtin_amdgcn_mfma_f32_16x16x32_bf16(af[i], ba[j], accA[i][j], 0, 0, 0);
                    accG[i][j] = __builtin_amdgcn_mfma_f32_16x16x32_bf16(af[i], bg[j], accG[i][j], 0, 0, 0);
                }
        }
    };

    int nk2 = Kk >> 6;
    STAGE2(0, 0);
    __syncthreads();
    for (int kt = 1; kt < nk2; kt++) {
        STAGE2(kt & 1, kt << 6);
        COMP2((kt - 1) & 1);
        __syncthreads();
    }
    COMP2((nk2 - 1) & 1);

    int rbase = quad * 4;
#pragma unroll
    for (int i = 0; i < 2; i++) {
#pragma unroll
        for (int j = 0; j < 2; j++) {
            int n = n0 + wn + j * 16 + rl;
            float bva = bias[n], bvg = bias[512 + n];
#pragma unroll
            for (int r = 0; r < 4; r++) {
                int m = m0 + wm + i * 16 + rbase + r;
                float a = accA[i][j][r] + bva;
                float g = accG[i][j][r] + bvg;
                Cv[(size_t)m * 512 + n] = f2bf(a * sigm(g));
            }
        }
    }
}

// ---------- fused flash attention v2 + T5 setprio (R10) ----------
__global__ __launch_bounds__(256) void fattn_k(
    const u16* __restrict__ QU, const u16* __restrict__ QV,
    const u16* __restrict__ Kb, const u16* __restrict__ Pbf,
    const u16* __restrict__ VT, u16* __restrict__ ctx) {
    __shared__ u16 arr[19072];            // 38,144 B -> 4 blocks/CU by LDS
    u16* sRect = arr;                     // bd shifted: 32 rows x stride 524 (scalar acc)
    u16* sP = arr;                        // alias: probs 32 x stride 520 (b128 reads)
    u16* sCtx = arr + 16768;              // 32 x 64 (disjoint from sP)
    float* sRed = (float*)(arr + 18816);  // 32 x 4 floats

    int tid = threadIdx.x;
    int lane = tid & 63, w = tid >> 6;
    int quad = lane >> 4, col = lane & 15;
    int nh = blockIdx.x, h = nh & 7, nb = nh >> 3;
    int m0 = blockIdx.y << 5;             // 32 q-rows per block
    int nlo = 480 - m0;                   // P window: rows nlo..nlo+543 (<=1023)

    const u16* QVz = QV + ((size_t)nh << 15);
    const u16* QUz = QU + ((size_t)nh << 15);
    const u16* Kz  = Kb + ((size_t)nh << 15);
    const u16* Vz  = VT + ((size_t)nh << 15);
    const u16* Pb  = Pbf + ((size_t)h << 16);

    // ---- phase 1: bd(32x544) = QV_tile . P^T, per-tile accumulators retired to sRect ----
    bf16x8 av[2][2];
#pragma unroll
    for (int ks = 0; ks < 2; ks++)
#pragma unroll
        for (int t = 0; t < 2; t++)
            av[ks][t] = *(const bf16x8*)(QVz + ((size_t)(m0 + t * 16 + col) << 6) + (ks << 5) + quad * 8);
    __builtin_amdgcn_s_setprio(1);
#pragma unroll
    for (int idx = 0; idx < 9; idx++) {
        int nt = w + (idx << 2);
        if (nt < 34) {
            int crow = nt * 16 + col;
            const u16* pb = Pb + ((size_t)(nlo + crow) << 6) + quad * 8;
            f32x4 b0 = (f32x4){0.f, 0.f, 0.f, 0.f};
            f32x4 b1 = (f32x4){0.f, 0.f, 0.f, 0.f};
#pragma unroll
            for (int ks = 0; ks < 2; ks++) {
                bf16x8 bfr = *(const bf16x8*)(pb + (ks << 5));
                b0 = __builtin_amdgcn_mfma_f32_16x16x32_bf16(av[ks][0], bfr, b0, 0, 0, 0);
                b1 = __builtin_amdgcn_mfma_f32_16x16x32_bf16(av[ks][1], bfr, b1, 0, 0, 0);
            }
            // shifted write: rect col c -> j = c + ml - 31; stride 524
#pragma unroll
            for (int r = 0; r < 4; r++) {
                int ml0 = quad * 4 + r;
                int j0 = crow + ml0 - 31;
                if (j0 >= 0 && j0 < 512) sRect[ml0 * 524 + j0] = f2bf(b0[r]);
                int ml1 = ml0 + 16;
                int j1 = crow + ml1 - 31;
                if (j1 >= 0 && j1 < 512) sRect[ml1 * 524 + j1] = f2bf(b1[r]);
            }
        }
    }
    __builtin_amdgcn_s_setprio(0);

    // ---- phase 2: ac(32x512) = QU_tile . K^T (direct reads, no barriers) ----
    bf16x8 au[2][2];
#pragma unroll
    for (int ks = 0; ks < 2; ks++)
#pragma unroll
        for (int t = 0; t < 2; t++)
            au[ks][t] = *(const bf16x8*)(QUz + ((size_t)(m0 + t * 16 + col) << 6) + (ks << 5) + quad * 8);
    f32x4 ac[2][8];
#pragma unroll
    for (int t = 0; t < 2; t++)
#pragma unroll
        for (int jt = 0; jt < 8; jt++) ac[t][jt] = (f32x4){0.f, 0.f, 0.f, 0.f};
    __builtin_amdgcn_s_setprio(1);
#pragma unroll
    for (int jt = 0; jt < 8; jt++) {
        const u16* kp = Kz + ((size_t)((w << 7) + jt * 16 + col) << 6) + quad * 8;
#pragma unroll
        for (int ks = 0; ks < 2; ks++) {
            bf16x8 bfr = *(const bf16x8*)(kp + (ks << 5));
            ac[0][jt] = __builtin_amdgcn_mfma_f32_16x16x32_bf16(au[ks][0], bfr, ac[0][jt], 0, 0, 0);
            ac[1][jt] = __builtin_amdgcn_mfma_f32_16x16x32_bf16(au[ks][1], bfr, ac[1][jt], 0, 0, 0);
        }
    }
    __builtin_amdgcn_s_setprio(0);
    __syncthreads();  // all sRect writes visible before phase-3 reads

    // ---- phase 3: shifted add + scale + softmax over j ----
    float rmax[2][4];
#pragma unroll
    for (int t = 0; t < 2; t++)
#pragma unroll
        for (int r = 0; r < 4; r++) rmax[t][r] = -1e30f;
#pragma unroll
    for (int jt = 0; jt < 8; jt++) {
        int j = (w << 7) + jt * 16 + col;
#pragma unroll
        for (int t = 0; t < 2; t++)
#pragma unroll
            for (int r = 0; r < 4; r++) {
                int ml = t * 16 + quad * 4 + r;
                float v = (ac[t][jt][r] + bf2f(sRect[ml * 524 + j])) * 0.125f;
                ac[t][jt][r] = v;
                rmax[t][r] = fmaxf(rmax[t][r], v);
            }
    }
#pragma unroll
    for (int o = 1; o <= 8; o <<= 1)
#pragma unroll
        for (int t = 0; t < 2; t++)
#pragma unroll
            for (int r = 0; r < 4; r++) rmax[t][r] = fmaxf(rmax[t][r], __shfl_xor(rmax[t][r], o));
    if (col == 0)
#pragma unroll
        for (int t = 0; t < 2; t++)
#pragma unroll
            for (int r = 0; r < 4; r++) sRed[(t * 16 + quad * 4 + r) * 4 + w] = rmax[t][r];
    __syncthreads();
    float gmax[2][4], psum[2][4];
#pragma unroll
    for (int t = 0; t < 2; t++)
#pragma unroll
        for (int r = 0; r < 4; r++) {
            int ml = t * 16 + quad * 4 + r;
            gmax[t][r] = fmaxf(fmaxf(sRed[ml * 4 + 0], sRed[ml * 4 + 1]),
                               fmaxf(sRed[ml * 4 + 2], sRed[ml * 4 + 3]));
            psum[t][r] = 0.f;
        }
    __syncthreads();
#pragma unroll
    for (int jt = 0; jt < 8; jt++)
#pragma unroll
        for (int t = 0; t < 2; t++)
#pragma unroll
            for (int r = 0; r < 4; r++) {
                float e = __expf(ac[t][jt][r] - gmax[t][r]);
                ac[t][jt][r] = e;
                psum[t][r] += e;
            }
#pragma unroll
    for (int o = 1; o <= 8; o <<= 1)
#pragma unroll
        for (int t = 0; t < 2; t++)
#pragma unroll
            for (int r = 0; r < 4; r++) psum[t][r] += __shfl_xor(psum[t][r], o);
    if (col == 0)
#pragma unroll
        for (int t = 0; t < 2; t++)
#pragma unroll
            for (int r = 0; r < 4; r++) sRed[(t * 16 + quad * 4 + r) * 4 + w] = psum[t][r];
    __syncthreads();
    float rinv[2][4];
#pragma unroll
    for (int t = 0; t < 2; t++)
#pragma unroll
        for (int r = 0; r < 4; r++) {
            int ml = t * 16 + quad * 4 + r;
            rinv[t][r] = 1.f / (sRed[ml * 4 + 0] + sRed[ml * 4 + 1] + sRed[ml * 4 + 2] + sRed[ml * 4 + 3]);
        }

    // ---- phase 4: probs -> sP (stride 520; sRect reads are >=2 barriers past) ----
#pragma unroll
    for (int jt = 0; jt < 8; jt++) {
        int j = (w << 7) + jt * 16 + col;
#pragma unroll
        for (int t = 0; t < 2; t++)
#pragma unroll
            for (int r = 0; r < 4; r++)
                sP[(t * 16 + quad * 4 + r) * 520 + j] = f2bf(ac[t][jt][r] * rinv[t][r]);
    }
    __syncthreads();

    // ---- phase 5: ctx(32x64) = P(32x512) . V^T, V fragments direct from L2 ----
    f32x4 cacc[2];
    cacc[0] = (f32x4){0.f, 0.f, 0.f, 0.f};
    cacc[1] = (f32x4){0.f, 0.f, 0.f, 0.f};
    {
        const u16* vp = Vz + ((size_t)((w << 4) + col) << 9) + quad * 8;
        __builtin_amdgcn_s_setprio(1);
#pragma unroll
        for (int kc = 0; kc < 2; kc++)
#pragma unroll
            for (int s2 = 0; s2 < 8; s2++) {
                int ko = (kc << 8) + (s2 << 5);
                bf16x8 a0 = *(const bf16x8*)(sP + col * 520 + ko + quad * 8);
                bf16x8 a1 = *(const bf16x8*)(sP + (col + 16) * 520 + ko + quad * 8);
                bf16x8 bfr = *(const bf16x8*)(vp + ko);
                cacc[0] = __builtin_amdgcn_mfma_f32_16x16x32_bf16(a0, bfr, cacc[0], 0, 0, 0);
                cacc[1] = __builtin_amdgcn_mfma_f32_16x16x32_bf16(a1, bfr, cacc[1], 0, 0, 0);
            }
        __builtin_amdgcn_s_setprio(0);
    }

    // ---- phase 6: ctx tile -> LDS (disjoint region) -> coalesced 16B stores ----
#pragma unroll
    for (int t = 0; t < 2; t++)
#pragma unroll
        for (int r = 0; r < 4; r++)
            sCtx[(t * 16 + quad * 4 + r) * 64 + (w << 4) + col] = f2bf(cacc[t][r]);
    __syncthreads();
    {
        int row = tid >> 3, seg = tid & 7;
        u16* dst = ctx + (((size_t)((m0 + row) * 16 + nb)) << 9) + (h << 6) + seg * 8;
        *(uint4*)dst = *(const uint4*)(sCtx + row * 64 + seg * 8);
    }
}

// ---------- repack qkv: vectorized, VT via LDS transpose (coalesced writes) ----------
__global__ __launch_bounds__(256) void repack_k(const u16* __restrict__ qkv,
                                                const float* __restrict__ bu,
                                                const float* __restrict__ bv,
                                                u16* __restrict__ QU, u16* __restrict__ QV,
                                                u16* __restrict__ Kb, u16* __restrict__ VT) {
    __shared__ u16 sV[64 * 72];  // 9216 B, stride 72 (8-aligned, bank step 4)
    int nh = blockIdx.x, h = nh & 7, n = nh >> 3;
    int l0 = blockIdx.y << 6;
    int tid = threadIdx.x;
    int d8 = (tid & 7) << 3;
    float bub[8], bvb[8];
#pragma unroll
    for (int e = 0; e < 8; e++) {
        bub[e] = bu[h * 64 + d8 + e];
        bvb[e] = bv[h * 64 + d8 + e];
    }
#pragma unroll
    for (int rep = 0; rep < 2; rep++) {
        int ll = (tid >> 3) + rep * 32;
        int l = l0 + ll;
        size_t base = (size_t)(l * 16 + n) * 1536 + h * 64 + d8;
        u16x8 q = *(const u16x8*)(qkv + base);
        u16x8 k = *(const u16x8*)(qkv + base + 512);
        u16x8 v = *(const u16x8*)(qkv + base + 1024);
        u16x8 qu, qv;
#pragma unroll
        for (int e = 0; e < 8; e++) {
            float qf = bf2f(q[e]);
            qu[e] = f2bf(qf + bub[e]);
            qv[e] = f2bf(qf + bvb[e]);
        }
        size_t o = ((size_t)nh * 512 + l) * 64 + d8;
        *(u16x8*)(QU + o) = qu;
        *(u16x8*)(QV + o) = qv;
        *(u16x8*)(Kb + o) = k;
        *(u16x8*)(sV + ll * 72 + d8) = v;
    }
    __syncthreads();
    int d = tid >> 2, ls = (tid & 3) << 4;
    u16 tmp[16];
#pragma unroll
    for (int e = 0; e < 16; e++) tmp[e] = sV[(ls + e) * 72 + d];
    u16* dst = VT + ((size_t)nh * 64 + d) * 512 + l0 + ls;
    *(u16x8*)(dst) = *(const u16x8*)(tmp);
    *(u16x8*)(dst + 8) = *(const u16x8*)(tmp + 8);
}

// ---------- depthwise conv: sliding window, 16 outputs per thread ----------
__global__ __launch_bounds__(256) void dwconv_k(
    const u16* __restrict__ g, const float* __restrict__ w, const float* __restrict__ wb,
    const float* __restrict__ bng, const float* __restrict__ bnb, const float* __restrict__ bnm,
    const float* __restrict__ bnv, u16* __restrict__ out) {
    int idx = blockIdx.x * 256 + threadIdx.x;  // 262144 threads
    int c = idx & 511;
    int t = idx >> 9;
    int n = t & 15, l0 = (t >> 4) << 4;
    float win[46];
#pragma unroll
    for (int q = 0; q < 46; q++) {
        int ll = l0 - 15 + q;
        win[q] = (ll >= 0 && ll < 512) ? bf2f(g[((size_t)(ll * 16 + n) << 9) + c]) : 0.f;
    }
    float wgt[31];
#pragma unroll
    for (int k = 0; k < 31; k++) wgt[k] = w[c * 31 + k];
    float ivg = rsqrtf(bnv[c] + 1e-5f) * bng[c];
    float mc = bnm[c], bc = bnb[c], wbc = wb[c];
#pragma unroll
    for (int r = 0; r < 16; r++) {
        float acc = 0.f;
#pragma unroll
        for (int k = 0; k < 31; k++) acc += wgt[k] * win[r + k];
        acc += wbc;
        float y = (acc - mc) * ivg + bc;
        y = y * sigm(y);
        out[((size_t)((l0 + r) * 16 + n) << 9) + c] = f2bf(y);
    }
}

// ---------- launch ----------
extern "C" void kernel_launch(void* const* d_in, const int* in_sizes, int n_in,
                              void* d_out, int out_size, void* d_ws, size_t ws_size,
                              hipStream_t stream) {
    const float* src      = (const float*)d_in[0];
    const float* pos_emb  = (const float*)d_in[1];
    const float* ffm_w1   = (const float*)d_in[2];
    const float* ffm_b1   = (const float*)d_in[3];
    const float* ffm_w2   = (const float*)d_in[4];
    const float* ffm_b2   = (const float*)d_in[5];
    const float* ff_w1    = (const float*)d_in[6];
    const float* ff_b1    = (const float*)d_in[7];
    const float* ff_w2    = (const float*)d_in[8];
    const float* ff_b2    = (const float*)d_in[9];
    const float* in_w     = (const float*)d_in[10];
    const float* in_b     = (const float*)d_in[11];
    const float* out_w    = (const float*)d_in[12];
    const float* out_b    = (const float*)d_in[13];
    const float* pos_w    = (const float*)d_in[14];
    const float* bu       = (const float*)d_in[15];
    const float* bv       = (const float*)d_in[16];
    const float* pw1_w    = (const float*)d_in[17];
    const float* pw1_b    = (const float*)d_in[18];
    const float* dw_w     = (const float*)d_in[19];
    const float* dw_b     = (const float*)d_in[20];
    const float* bng      = (const float*)d_in[21];
    const float* bnb      = (const float*)d_in[22];
    const float* bnm      = (const float*)d_in[23];
    const float* bnv      = (const float*)d_in[24];
    const float* pw2_w    = (const float*)d_in[25];
    const float* pw2_b    = (const float*)d_in[26];
    const float* ln_ffm_g = (const float*)d_in[27];
    const float* ln_ffm_b = (const float*)d_in[28];
    const float* ln_mha_g = (const float*)d_in[29];
    const float* ln_mha_b = (const float*)d_in[30];
    const float* ln_cv_g  = (const float*)d_in[31];
    const float* ln_cv_b  = (const float*)d_in[32];
    const float* ln_ff_g  = (const float*)d_in[33];
    const float* ln_ff_b  = (const float*)d_in[34];
    const float* ln_fin_g = (const float*)d_in[35];
    const float* ln_fin_b = (const float*)d_in[36];
    (void)in_sizes; (void)n_in; (void)out_size; (void)ws_size;

    // ---- workspace layout in u16 units; total ~117 MiB ----
    const size_t MEG = 1048576;
    u16* U = (u16*)d_ws;
    float* xA = (float*)U;                // 8M u16; Pbf aliases during attention
    u16* Pbf = U;                         // 524288 u16 (8 x 1024 x 64)
    float* xB = (float*)(U + 8 * MEG);    // 8M
    u16* LNB = U + 16 * MEG;              // 4M
    u16* BIG = U + 20 * MEG;              // 16M: h1 / qkv
    u16* QU = U + 36 * MEG;               // 4M
    u16* QV = U + 40 * MEG;               // 4M
    u16* Kb = U + 44 * MEG;               // 4M
    u16* VT = U + 48 * MEG;               // 4M
    u16* WB = U + 52 * MEG;               // 6,815,232 weights bf16
    u16* w_ffm1 = WB;
    u16* w_ffm2 = WB + 1 * MEG;
    u16* w_ff1  = WB + 2 * MEG;
    u16* w_ff2  = WB + 3 * MEG;
    u16* w_in   = WB + 4 * MEG;
    u16* w_out  = WB + 4 * MEG + 786432;
    u16* w_pw1  = WB + 5 * MEG;
    u16* w_pw2  = WB + 5 * MEG + 524288;
    u16* w_pos  = WB + 6029312;           // 512x512
    u16* w_pe   = WB + 6291456;           // 1023x512
    u16* CTX = LNB;
    u16* GLU = QU;
    u16* CACT = QV;

    // ---- fused: cast all weights + ln_ffm (one dispatch) ----
    fusedpre_k<<<8704, 256, 0, stream>>>(ffm_w1, ffm_w2, ff_w1, ff_w2, in_w, out_w,
                                         pw1_w, pw2_w, pos_w, pos_emb, WB,
                                         src, ln_ffm_g, ln_ffm_b, LNB);

    // ---- FFN macaron: xB = src + 0.5*ffn(ln(src)) ----
    mgemm64_k<<<dim3(128, 32), 256, 0, stream>>>(LNB, w_ffm1, ffm_b1, nullptr, BIG,
                                                 8192, 2048, 512, 0.f, 1, 1);
    mgemm64_k<<<dim3(128, 8), 256, 0, stream>>>(BIG, w_ffm2, ffm_b2, src, xB,
                                                8192, 512, 2048, 0.5f, 0, 0);

    // ---- attention: xA = xB + attn(ln(xB)) ----
    ln512_k<true><<<2048, 256, 0, stream>>>(xB, ln_mha_g, ln_mha_b, LNB);
    qkvpos_k<<<dim3(128, 25), 256, 0, stream>>>(LNB, w_in, in_b, BIG,
                                                w_pe, w_pos, Pbf);
    repack_k<<<dim3(128, 8), 256, 0, stream>>>(BIG, bu, bv, QU, QV, Kb, VT);
    fattn_k<<<dim3(128, 16), 256, 0, stream>>>(QU, QV, Kb, Pbf, VT, CTX);
    mgemm64_k<<<dim3(128, 8), 256, 0, stream>>>(CTX, w_out, out_b, xB, xA,
                                                8192, 512, 512, 1.f, 0, 0);

    // ---- conv module: xB = xA + conv(ln(xA)) ----
    ln512_k<true><<<2048, 256, 0, stream>>>(xA, ln_cv_g, ln_cv_b, LNB);
    mgemmglu_k<<<dim3(128, 8), 256, 0, stream>>>(LNB, w_pw1, pw1_b, GLU, 512);
    dwconv_k<<<1024, 256, 0, stream>>>(GLU, dw_w, dw_b, bng, bnb, bnm, bnv, CACT);
    mgemm64_k<<<dim3(128, 8), 256, 0, stream>>>(CACT, w_pw2, pw2_b, xA, xB,
                                                8192, 512, 512, 1.f, 0, 0);

    // ---- FFN 2: xA = xB + 0.5*ffn(ln(xB)) ----
    ln512_k<true><<<2048, 256, 0, stream>>>(xB, ln_ff_g, ln_ff_b, LNB);
    mgemm64_k<<<dim3(128, 32), 256, 0, stream>>>(LNB, w_ff1, ff_b1, nullptr, BIG,
                                                 8192, 2048, 512, 0.f, 1, 1);
    mgemm64_k<<<dim3(128, 8), 256, 0, stream>>>(BIG, w_ff2, ff_b2, xB, xA,
                                                8192, 512, 2048, 0.5f, 0, 0);

    // ---- final LN -> fp32 out ----
    ln512_k<false><<<2048, 256, 0, stream>>>(xA, ln_fin_g, ln_fin_b, (float*)d_out);
}

// Round 12
// 503.499 us; speedup vs baseline: 1.2669x; 1.0007x over previous
//
#include <hip/hip_runtime.h>
#include <cstdint>
#include <cstddef>

typedef unsigned short u16;
typedef __attribute__((ext_vector_type(4))) float f32x4;
typedef __attribute__((ext_vector_type(8))) short bf16x8;
typedef __attribute__((ext_vector_type(8))) unsigned short u16x8;

// ---------- helpers ----------
__device__ __forceinline__ float sigm(float x) { return 1.f / (1.f + __expf(-x)); }
__device__ __forceinline__ float bf2f(u16 u) {
    union { unsigned int i; float f; } c; c.i = ((unsigned int)u) << 16; return c.f;
}
__device__ __forceinline__ u16 f2bf(float f) {
    union { float f; unsigned int i; } c; c.f = f;
    unsigned int x = c.i;
    x += 0x7fffu + ((x >> 16) & 1u);
    return (u16)(x >> 16);
}

// dims: D=512, H=8, DH=64, F=2048, K=31, L=512, N=16, M=8192

// ---------- fused prologue (R10): weight-cast (blocks 0..6655) + first LN (6656..8703) ----------
__global__ __launch_bounds__(256) void fusedpre_k(
    const float* __restrict__ s0, const float* __restrict__ s1,
    const float* __restrict__ s2, const float* __restrict__ s3,
    const float* __restrict__ s4, const float* __restrict__ s5,
    const float* __restrict__ s6, const float* __restrict__ s7,
    const float* __restrict__ s8, const float* __restrict__ s9,
    u16* __restrict__ dst,
    const float* __restrict__ x, const float* __restrict__ g,
    const float* __restrict__ b, u16* __restrict__ lnout) {
    if (blockIdx.x < 6656) {
        int i = (blockIdx.x * 256 + threadIdx.x) << 2;
        if (i >= 6815232) return;
        const float* s; int off;
        if      (i < 1048576) { s = s0; off = 0; }
        else if (i < 2097152) { s = s1; off = 1048576; }
        else if (i < 3145728) { s = s2; off = 2097152; }
        else if (i < 4194304) { s = s3; off = 3145728; }
        else if (i < 4980736) { s = s4; off = 4194304; }
        else if (i < 5242880) { s = s5; off = 4980736; }
        else if (i < 5767168) { s = s6; off = 5242880; }
        else if (i < 6029312) { s = s7; off = 5767168; }
        else if (i < 6291456) { s = s8; off = 6029312; }
        else                  { s = s9; off = 6291456; }
        float4 v = *(const float4*)(s + (i - off));
        union { unsigned int u[2]; } o;
        o.u[0] = (unsigned int)f2bf(v.x) | ((unsigned int)f2bf(v.y) << 16);
        o.u[1] = (unsigned int)f2bf(v.z) | ((unsigned int)f2bf(v.w) << 16);
        *(uint2*)(dst + i) = *(const uint2*)o.u;
    } else {
        int row = (blockIdx.x - 6656) * 4 + (threadIdx.x >> 6);
        int lane = threadIdx.x & 63;
        const float* xr = x + (size_t)row * 512 + lane * 8;
        float4 v0 = *(const float4*)(xr);
        float4 v1 = *(const float4*)(xr + 4);
        float va[8] = {v0.x, v0.y, v0.z, v0.w, v1.x, v1.y, v1.z, v1.w};
        float s = 0.f;
#pragma unroll
        for (int t = 0; t < 8; t++) s += va[t];
#pragma unroll
        for (int o = 32; o > 0; o >>= 1) s += __shfl_xor(s, o);
        float m = s * (1.0f / 512.0f);
        float q = 0.f;
#pragma unroll
        for (int t = 0; t < 8; t++) { float d = va[t] - m; q += d * d; }
#pragma unroll
        for (int o = 32; o > 0; o >>= 1) q += __shfl_xor(q, o);
        float inv = rsqrtf(q * (1.0f / 512.0f) + 1e-5f);
        int cb = lane * 8;
        u16* o = lnout + (size_t)row * 512 + cb;
#pragma unroll
        for (int t = 0; t < 8; t++)
            o[t] = f2bf((va[t] - m) * inv * g[cb + t] + b[cb + t]);
    }
}

// ---------- LayerNorm over 512 (fp32 in), 4 rows per 256-thread block ----------
template <bool OUTBF>
__global__ __launch_bounds__(256) void ln512_k(const float* __restrict__ x,
                                               const float* __restrict__ g,
                                               const float* __restrict__ b,
                                               void* __restrict__ outv) {
    int row = blockIdx.x * 4 + (threadIdx.x >> 6);
    int lane = threadIdx.x & 63;
    const float* xr = x + (size_t)row * 512 + lane * 8;
    float4 v0 = *(const float4*)(xr);
    float4 v1 = *(const float4*)(xr + 4);
    float va[8] = {v0.x, v0.y, v0.z, v0.w, v1.x, v1.y, v1.z, v1.w};
    float s = 0.f;
#pragma unroll
    for (int t = 0; t < 8; t++) s += va[t];
#pragma unroll
    for (int o = 32; o > 0; o >>= 1) s += __shfl_xor(s, o);
    float m = s * (1.0f / 512.0f);
    float q = 0.f;
#pragma unroll
    for (int t = 0; t < 8; t++) { float d = va[t] - m; q += d * d; }
#pragma unroll
    for (int o = 32; o > 0; o >>= 1) q += __shfl_xor(q, o);
    float inv = rsqrtf(q * (1.0f / 512.0f) + 1e-5f);
    int cb = lane * 8;
    if (OUTBF) {
        u16* o = (u16*)outv + (size_t)row * 512 + cb;
#pragma unroll
        for (int t = 0; t < 8; t++)
            o[t] = f2bf((va[t] - m) * inv * g[cb + t] + b[cb + t]);
    } else {
        float* o = (float*)outv + (size_t)row * 512 + cb;
#pragma unroll
        for (int t = 0; t < 8; t++)
            o[t] = (va[t] - m) * inv * g[cb + t] + b[cb + t];
    }
}

// ---------- MFMA GEMM 64x64 tile, 2 K-subtiles per barrier (R9) ----------
__global__ __launch_bounds__(256) void mgemm64_k(
    const u16* __restrict__ A, const u16* __restrict__ B, const float* __restrict__ bias,
    const float* __restrict__ add, void* __restrict__ Cv,
    int M, int Nn, int Kk, float coef, int act, int outbf) {
    __shared__ u16 lA[4][2048];
    __shared__ u16 lB[4][2048];
    int tid = threadIdx.x;
    int lane = tid & 63;
    int w = tid >> 6;
    int quad = lane >> 4, rl = lane & 15;
    int wm = (w >> 1) * 32, wn = (w & 1) * 32;
    int m0 = blockIdx.x << 6, n0 = blockIdx.y << 6;

    f32x4 acc[2][2];
#pragma unroll
    for (int i = 0; i < 2; i++)
#pragma unroll
        for (int j = 0; j < 2; j++) acc[i][j] = (f32x4){0.f, 0.f, 0.f, 0.f};

    int srow = tid >> 2;          // 0..63
    int scol = (tid & 3) << 3;    // 0,8,16,24
    const u16* gA = A + (size_t)(m0 + srow) * Kk + scol;
    const u16* gB = B + (size_t)(n0 + srow) * Kk + scol;
    int lso = tid * 8;
    int lra = wm * 32 + rl * 32 + quad * 8;   // row-stride 32 u16 (64B)
    int lrb = wn * 32 + rl * 32 + quad * 8;

    auto STAGE2 = [&](int p, int k0) {
#pragma unroll
        for (int s = 0; s < 2; s++) {
            __builtin_amdgcn_global_load_lds(
                (const __attribute__((address_space(1))) void*)(gA + k0 + (s << 5)),
                (__attribute__((address_space(3))) void*)(lA[(p << 1) + s] + lso), 16, 0, 0);
            __builtin_amdgcn_global_load_lds(
                (const __attribute__((address_space(1))) void*)(gB + k0 + (s << 5)),
                (__attribute__((address_space(3))) void*)(lB[(p << 1) + s] + lso), 16, 0, 0);
        }
    };
    auto COMP2 = [&](int p) {
#pragma unroll
        for (int s = 0; s < 2; s++) {
            bf16x8 af[2], bf[2];
#pragma unroll
            for (int t = 0; t < 2; t++) {
                af[t] = *(const bf16x8*)(lA[(p << 1) + s] + lra + t * 512);
                bf[t] = *(const bf16x8*)(lB[(p << 1) + s] + lrb + t * 512);
            }
#pragma unroll
            for (int i = 0; i < 2; i++)
#pragma unroll
                for (int j = 0; j < 2; j++)
                    acc[i][j] = __builtin_amdgcn_mfma_f32_16x16x32_bf16(af[i], bf[j], acc[i][j], 0, 0, 0);
        }
    };

    int nk2 = Kk >> 6;   // K divisible by 64 for all call sites (512/2048)
    STAGE2(0, 0);
    __syncthreads();
    for (int kt = 1; kt < nk2; kt++) {
        STAGE2(kt & 1, kt << 6);
        COMP2((kt - 1) & 1);
        __syncthreads();
    }
    COMP2((nk2 - 1) & 1);

    int rbase = quad * 4;
#pragma unroll
    for (int i = 0; i < 2; i++) {
#pragma unroll
        for (int j = 0; j < 2; j++) {
            int n = n0 + wn + j * 16 + rl;
            float bv = bias ? bias[n] : 0.f;
#pragma unroll
            for (int r = 0; r < 4; r++) {
                int m = m0 + wm + i * 16 + rbase + r;
                float c = acc[i][j][r] + bv;
                if (act == 1) c *= sigm(c);
                size_t o = (size_t)m * Nn + n;
                if (add) c = add[o] + coef * c;
                if (outbf) ((u16*)Cv)[o] = f2bf(c);
                else ((float*)Cv)[o] = c;
            }
        }
    }
}

// ---------- fused in-proj GEMM + pos GEMM (R10): grid (128, 25) ----------
__global__ __launch_bounds__(256) void qkvpos_k(
    const u16* __restrict__ A, const u16* __restrict__ B, const float* __restrict__ bias,
    u16* __restrict__ C, const u16* __restrict__ pA, const u16* __restrict__ pB,
    u16* __restrict__ Pbf) {
    __shared__ u16 lA[4][2048];
    __shared__ u16 lB[4][2048];
    const int Kk = 512;
    int tid = threadIdx.x;
    int lane = tid & 63;
    int w = tid >> 6;
    int quad = lane >> 4, rl = lane & 15;
    int wm = (w >> 1) * 32, wn = (w & 1) * 32;
    int srow = tid >> 2;
    int scol = (tid & 3) << 3;
    int lso = tid * 8;
    int lra = wm * 32 + rl * 32 + quad * 8;
    int lrb = wn * 32 + rl * 32 + quad * 8;

    f32x4 acc[2][2];
#pragma unroll
    for (int i = 0; i < 2; i++)
#pragma unroll
        for (int j = 0; j < 2; j++) acc[i][j] = (f32x4){0.f, 0.f, 0.f, 0.f};

    bool ispos = (blockIdx.y == 24);
    int m0, n0;
    const u16 *gA, *gB;
    if (!ispos) {
        m0 = blockIdx.x << 6; n0 = blockIdx.y << 6;
        gA = A + (size_t)(m0 + srow) * Kk + scol;
        gB = B + (size_t)(n0 + srow) * Kk + scol;
    } else {
        int bx = blockIdx.x;
        m0 = (bx >> 3) << 6; n0 = (bx & 7) << 6;
        int ar = m0 + srow; if (ar > 1022) ar = 1022;
        gA = pA + (size_t)ar * Kk + scol;
        gB = pB + (size_t)(n0 + srow) * Kk + scol;
    }

    auto STAGE2 = [&](int p, int k0) {
#pragma unroll
        for (int s = 0; s < 2; s++) {
            __builtin_amdgcn_global_load_lds(
                (const __attribute__((address_space(1))) void*)(gA + k0 + (s << 5)),
                (__attribute__((address_space(3))) void*)(lA[(p << 1) + s] + lso), 16, 0, 0);
            __builtin_amdgcn_global_load_lds(
                (const __attribute__((address_space(1))) void*)(gB + k0 + (s << 5)),
                (__attribute__((address_space(3))) void*)(lB[(p << 1) + s] + lso), 16, 0, 0);
        }
    };
    auto COMP2 = [&](int p) {
#pragma unroll
        for (int s = 0; s < 2; s++) {
            bf16x8 af[2], bf[2];
#pragma unroll
            for (int t = 0; t < 2; t++) {
                af[t] = *(const bf16x8*)(lA[(p << 1) + s] + lra + t * 512);
                bf[t] = *(const bf16x8*)(lB[(p << 1) + s] + lrb + t * 512);
            }
#pragma unroll
            for (int i = 0; i < 2; i++)
#pragma unroll
                for (int j = 0; j < 2; j++)
                    acc[i][j] = __builtin_amdgcn_mfma_f32_16x16x32_bf16(af[i], bf[j], acc[i][j], 0, 0, 0);
        }
    };

    const int nk2 = 8;  // K=512
    STAGE2(0, 0);
    __syncthreads();
    for (int kt = 1; kt < nk2; kt++) {
        STAGE2(kt & 1, kt << 6);
        COMP2((kt - 1) & 1);
        __syncthreads();
    }
    COMP2((nk2 - 1) & 1);

    int rbase = quad * 4;
    if (!ispos) {
#pragma unroll
        for (int i = 0; i < 2; i++) {
#pragma unroll
            for (int j = 0; j < 2; j++) {
                int n = n0 + wn + j * 16 + rl;
                float bv = bias[n];
#pragma unroll
                for (int r = 0; r < 4; r++) {
                    int m = m0 + wm + i * 16 + rbase + r;
                    C[(size_t)m * 1536 + n] = f2bf(acc[i][j][r] + bv);
                }
            }
        }
    } else {
#pragma unroll
        for (int i = 0; i < 2; i++) {
#pragma unroll
            for (int j = 0; j < 2; j++) {
                int n = n0 + wn + j * 16 + rl;
                int h = n >> 6, d = n & 63;
#pragma unroll
                for (int r = 0; r < 4; r++) {
                    int m = m0 + wm + i * 16 + rbase + r;
                    u16 val = (m < 1023) ? f2bf(acc[i][j][r]) : (u16)0;
                    Pbf[(((size_t)(h * 1024 + m)) << 6) + d] = val;
                }
            }
        }
    }
}

// ---------- pw1 GEMM with fused GLU epilogue, 2 K-subtiles per barrier (R9) ----------
__global__ __launch_bounds__(256) void mgemmglu_k(
    const u16* __restrict__ A, const u16* __restrict__ B, const float* __restrict__ bias,
    u16* __restrict__ Cv, int Kk) {
    __shared__ u16 lA[4][2048];
    __shared__ u16 lBa[4][2048];
    __shared__ u16 lBg[4][2048];
    int tid = threadIdx.x;
    int lane = tid & 63;
    int w = tid >> 6;
    int quad = lane >> 4, rl = lane & 15;
    int wm = (w >> 1) * 32, wn = (w & 1) * 32;
    int m0 = blockIdx.x << 6, n0 = blockIdx.y << 6;

    f32x4 accA[2][2], accG[2][2];
#pragma unroll
    for (int i = 0; i < 2; i++)
#pragma unroll
        for (int j = 0; j < 2; j++) {
            accA[i][j] = (f32x4){0.f, 0.f, 0.f, 0.f};
            accG[i][j] = (f32x4){0.f, 0.f, 0.f, 0.f};
        }

    int srow = tid >> 2;
    int scol = (tid & 3) << 3;
    const u16* gA  = A + (size_t)(m0 + srow) * Kk + scol;
    const u16* gBa = B + (size_t)(n0 + srow) * Kk + scol;
    const u16* gBg = B + (size_t)(512 + n0 + srow) * Kk + scol;
    int lso = tid * 8;
    int lra = wm * 32 + rl * 32 + quad * 8;
    int lrb = wn * 32 + rl * 32 + quad * 8;

    auto STAGE2 = [&](int p, int k0) {
#pragma unroll
        for (int s = 0; s < 2; s++) {
            __builtin_amdgcn_global_load_lds(
                (const __attribute__((address_space(1))) void*)(gA + k0 + (s << 5)),
                (__attribute__((address_space(3))) void*)(lA[(p << 1) + s] + lso), 16, 0, 0);
            __builtin_amdgcn_global_load_lds(
                (const __attribute__((address_space(1))) void*)(gBa + k0 + (s << 5)),
                (__attribute__((address_space(3))) void*)(lBa[(p << 1) + s] + lso), 16, 0, 0);
            __builtin_amdgcn_global_load_lds(
                (const __attribute__((address_space(1))) void*)(gBg + k0 + (s << 5)),
                (__attribute__((address_space(3))) void*)(lBg[(p << 1) + s] + lso), 16, 0, 0);
        }
    };
    auto COMP2 = [&](int p) {
#pragma unroll
        for (int s = 0; s < 2; s++) {
            bf16x8 af[2], ba[2], bg[2];
#pragma unroll
            for (int t = 0; t < 2; t++) {
                af[t] = *(const bf16x8*)(lA[(p << 1) + s] + lra + t * 512);
                ba[t] = *(const bf16x8*)(lBa[(p << 1) + s] + lrb + t * 512);
                bg[t] = *(const bf16x8*)(lBg[(p << 1) + s] + lrb + t * 512);
            }
#pragma unroll
            for (int i = 0; i < 2; i++)
#pragma unroll
                for (int j = 0; j < 2; j++) {
                    accA[i][j] = __builtin_amdgcn_mfma_f32_16x16x32_bf16(af[i], ba[j], accA[i][j], 0, 0, 0);
                    accG[i][j] = __builtin_amdgcn_mfma_f32_16x16x32_bf16(af[i], bg[j], accG[i][j], 0, 0, 0);
                }
        }
    };

    int nk2 = Kk >> 6;
    STAGE2(0, 0);
    __syncthreads();
    for (int kt = 1; kt < nk2; kt++) {
        STAGE2(kt & 1, kt << 6);
        COMP2((kt - 1) & 1);
        __syncthreads();
    }
    COMP2((nk2 - 1) & 1);

    int rbase = quad * 4;
#pragma unroll
    for (int i = 0; i < 2; i++) {
#pragma unroll
        for (int j = 0; j < 2; j++) {
            int n = n0 + wn + j * 16 + rl;
            float bva = bias[n], bvg = bias[512 + n];
#pragma unroll
            for (int r = 0; r < 4; r++) {
                int m = m0 + wm + i * 16 + rbase + r;
                float a = accA[i][j][r] + bva;
                float g = accG[i][j][r] + bvg;
                Cv[(size_t)m * 512 + n] = f2bf(a * sigm(g));
            }
        }
    }
}

// ---------- fused flash attention v2 (R11: setprio reverted — measured -1us) ----------
__global__ __launch_bounds__(256) void fattn_k(
    const u16* __restrict__ QU, const u16* __restrict__ QV,
    const u16* __restrict__ Kb, const u16* __restrict__ Pbf,
    const u16* __restrict__ VT, u16* __restrict__ ctx) {
    __shared__ u16 arr[19072];            // 38,144 B -> 4 blocks/CU by LDS
    u16* sRect = arr;                     // bd shifted: 32 rows x stride 524 (scalar acc)
    u16* sP = arr;                        // alias: probs 32 x stride 520 (b128 reads)
    u16* sCtx = arr + 16768;              // 32 x 64 (disjoint from sP)
    float* sRed = (float*)(arr + 18816);  // 32 x 4 floats

    int tid = threadIdx.x;
    int lane = tid & 63, w = tid >> 6;
    int quad = lane >> 4, col = lane & 15;
    int nh = blockIdx.x, h = nh & 7, nb = nh >> 3;
    int m0 = blockIdx.y << 5;             // 32 q-rows per block
    int nlo = 480 - m0;                   // P window: rows nlo..nlo+543 (<=1023)

    const u16* QVz = QV + ((size_t)nh << 15);
    const u16* QUz = QU + ((size_t)nh << 15);
    const u16* Kz  = Kb + ((size_t)nh << 15);
    const u16* Vz  = VT + ((size_t)nh << 15);
    const u16* Pb  = Pbf + ((size_t)h << 16);

    // ---- phase 1: bd(32x544) = QV_tile . P^T, per-tile accumulators retired to sRect ----
    bf16x8 av[2][2];
#pragma unroll
    for (int ks = 0; ks < 2; ks++)
#pragma unroll
        for (int t = 0; t < 2; t++)
            av[ks][t] = *(const bf16x8*)(QVz + ((size_t)(m0 + t * 16 + col) << 6) + (ks << 5) + quad * 8);
#pragma unroll
    for (int idx = 0; idx < 9; idx++) {
        int nt = w + (idx << 2);
        if (nt < 34) {
            int crow = nt * 16 + col;
            const u16* pb = Pb + ((size_t)(nlo + crow) << 6) + quad * 8;
            f32x4 b0 = (f32x4){0.f, 0.f, 0.f, 0.f};
            f32x4 b1 = (f32x4){0.f, 0.f, 0.f, 0.f};
#pragma unroll
            for (int ks = 0; ks < 2; ks++) {
                bf16x8 bfr = *(const bf16x8*)(pb + (ks << 5));
                b0 = __builtin_amdgcn_mfma_f32_16x16x32_bf16(av[ks][0], bfr, b0, 0, 0, 0);
                b1 = __builtin_amdgcn_mfma_f32_16x16x32_bf16(av[ks][1], bfr, b1, 0, 0, 0);
            }
            // shifted write: rect col c -> j = c + ml - 31; stride 524
#pragma unroll
            for (int r = 0; r < 4; r++) {
                int ml0 = quad * 4 + r;
                int j0 = crow + ml0 - 31;
                if (j0 >= 0 && j0 < 512) sRect[ml0 * 524 + j0] = f2bf(b0[r]);
                int ml1 = ml0 + 16;
                int j1 = crow + ml1 - 31;
                if (j1 >= 0 && j1 < 512) sRect[ml1 * 524 + j1] = f2bf(b1[r]);
            }
        }
    }

    // ---- phase 2: ac(32x512) = QU_tile . K^T (direct reads, no barriers) ----
    bf16x8 au[2][2];
#pragma unroll
    for (int ks = 0; ks < 2; ks++)
#pragma unroll
        for (int t = 0; t < 2; t++)
            au[ks][t] = *(const bf16x8*)(QUz + ((size_t)(m0 + t * 16 + col) << 6) + (ks << 5) + quad * 8);
    f32x4 ac[2][8];
#pragma unroll
    for (int t = 0; t < 2; t++)
#pragma unroll
        for (int jt = 0; jt < 8; jt++) ac[t][jt] = (f32x4){0.f, 0.f, 0.f, 0.f};
#pragma unroll
    for (int jt = 0; jt < 8; jt++) {
        const u16* kp = Kz + ((size_t)((w << 7) + jt * 16 + col) << 6) + quad * 8;
#pragma unroll
        for (int ks = 0; ks < 2; ks++) {
            bf16x8 bfr = *(const bf16x8*)(kp + (ks << 5));
            ac[0][jt] = __builtin_amdgcn_mfma_f32_16x16x32_bf16(au[ks][0], bfr, ac[0][jt], 0, 0, 0);
            ac[1][jt] = __builtin_amdgcn_mfma_f32_16x16x32_bf16(au[ks][1], bfr, ac[1][jt], 0, 0, 0);
        }
    }
    __syncthreads();  // all sRect writes visible before phase-3 reads

    // ---- phase 3: shifted add + scale + softmax over j ----
    float rmax[2][4];
#pragma unroll
    for (int t = 0; t < 2; t++)
#pragma unroll
        for (int r = 0; r < 4; r++) rmax[t][r] = -1e30f;
#pragma unroll
    for (int jt = 0; jt < 8; jt++) {
        int j = (w << 7) + jt * 16 + col;
#pragma unroll
        for (int t = 0; t < 2; t++)
#pragma unroll
            for (int r = 0; r < 4; r++) {
                int ml = t * 16 + quad * 4 + r;
                float v = (ac[t][jt][r] + bf2f(sRect[ml * 524 + j])) * 0.125f;
                ac[t][jt][r] = v;
                rmax[t][r] = fmaxf(rmax[t][r], v);
            }
    }
#pragma unroll
    for (int o = 1; o <= 8; o <<= 1)
#pragma unroll
        for (int t = 0; t < 2; t++)
#pragma unroll
            for (int r = 0; r < 4; r++) rmax[t][r] = fmaxf(rmax[t][r], __shfl_xor(rmax[t][r], o));
    if (col == 0)
#pragma unroll
        for (int t = 0; t < 2; t++)
#pragma unroll
            for (int r = 0; r < 4; r++) sRed[(t * 16 + quad * 4 + r) * 4 + w] = rmax[t][r];
    __syncthreads();
    float gmax[2][4], psum[2][4];
#pragma unroll
    for (int t = 0; t < 2; t++)
#pragma unroll
        for (int r = 0; r < 4; r++) {
            int ml = t * 16 + quad * 4 + r;
            gmax[t][r] = fmaxf(fmaxf(sRed[ml * 4 + 0], sRed[ml * 4 + 1]),
                               fmaxf(sRed[ml * 4 + 2], sRed[ml * 4 + 3]));
            psum[t][r] = 0.f;
        }
    __syncthreads();
#pragma unroll
    for (int jt = 0; jt < 8; jt++)
#pragma unroll
        for (int t = 0; t < 2; t++)
#pragma unroll
            for (int r = 0; r < 4; r++) {
                float e = __expf(ac[t][jt][r] - gmax[t][r]);
                ac[t][jt][r] = e;
                psum[t][r] += e;
            }
#pragma unroll
    for (int o = 1; o <= 8; o <<= 1)
#pragma unroll
        for (int t = 0; t < 2; t++)
#pragma unroll
            for (int r = 0; r < 4; r++) psum[t][r] += __shfl_xor(psum[t][r], o);
    if (col == 0)
#pragma unroll
        for (int t = 0; t < 2; t++)
#pragma unroll
            for (int r = 0; r < 4; r++) sRed[(t * 16 + quad * 4 + r) * 4 + w] = psum[t][r];
    __syncthreads();
    float rinv[2][4];
#pragma unroll
    for (int t = 0; t < 2; t++)
#pragma unroll
        for (int r = 0; r < 4; r++) {
            int ml = t * 16 + quad * 4 + r;
            rinv[t][r] = 1.f / (sRed[ml * 4 + 0] + sRed[ml * 4 + 1] + sRed[ml * 4 + 2] + sRed[ml * 4 + 3]);
        }

    // ---- phase 4: probs -> sP (stride 520; sRect reads are >=2 barriers past) ----
#pragma unroll
    for (int jt = 0; jt < 8; jt++) {
        int j = (w << 7) + jt * 16 + col;
#pragma unroll
        for (int t = 0; t < 2; t++)
#pragma unroll
            for (int r = 0; r < 4; r++)
                sP[(t * 16 + quad * 4 + r) * 520 + j] = f2bf(ac[t][jt][r] * rinv[t][r]);
    }
    __syncthreads();

    // ---- phase 5: ctx(32x64) = P(32x512) . V^T, V fragments direct from L2 ----
    f32x4 cacc[2];
    cacc[0] = (f32x4){0.f, 0.f, 0.f, 0.f};
    cacc[1] = (f32x4){0.f, 0.f, 0.f, 0.f};
    {
        const u16* vp = Vz + ((size_t)((w << 4) + col) << 9) + quad * 8;
#pragma unroll
        for (int kc = 0; kc < 2; kc++)
#pragma unroll
            for (int s2 = 0; s2 < 8; s2++) {
                int ko = (kc << 8) + (s2 << 5);
                bf16x8 a0 = *(const bf16x8*)(sP + col * 520 + ko + quad * 8);
                bf16x8 a1 = *(const bf16x8*)(sP + (col + 16) * 520 + ko + quad * 8);
                bf16x8 bfr = *(const bf16x8*)(vp + ko);
                cacc[0] = __builtin_amdgcn_mfma_f32_16x16x32_bf16(a0, bfr, cacc[0], 0, 0, 0);
                cacc[1] = __builtin_amdgcn_mfma_f32_16x16x32_bf16(a1, bfr, cacc[1], 0, 0, 0);
            }
    }

    // ---- phase 6: ctx tile -> LDS (disjoint region) -> coalesced 16B stores ----
#pragma unroll
    for (int t = 0; t < 2; t++)
#pragma unroll
        for (int r = 0; r < 4; r++)
            sCtx[(t * 16 + quad * 4 + r) * 64 + (w << 4) + col] = f2bf(cacc[t][r]);
    __syncthreads();
    {
        int row = tid >> 3, seg = tid & 7;
        u16* dst = ctx + (((size_t)((m0 + row) * 16 + nb)) << 9) + (h << 6) + seg * 8;
        *(uint4*)dst = *(const uint4*)(sCtx + row * 64 + seg * 8);
    }
}

// ---------- repack qkv: vectorized, VT via LDS transpose (coalesced writes) ----------
__global__ __launch_bounds__(256) void repack_k(const u16* __restrict__ qkv,
                                                const float* __restrict__ bu,
                                                const float* __restrict__ bv,
                                                u16* __restrict__ QU, u16* __restrict__ QV,
                                                u16* __restrict__ Kb, u16* __restrict__ VT) {
    __shared__ u16 sV[64 * 72];  // 9216 B, stride 72 (8-aligned, bank step 4)
    int nh = blockIdx.x, h = nh & 7, n = nh >> 3;
    int l0 = blockIdx.y << 6;
    int tid = threadIdx.x;
    int d8 = (tid & 7) << 3;
    float bub[8], bvb[8];
#pragma unroll
    for (int e = 0; e < 8; e++) {
        bub[e] = bu[h * 64 + d8 + e];
        bvb[e] = bv[h * 64 + d8 + e];
    }
#pragma unroll
    for (int rep = 0; rep < 2; rep++) {
        int ll = (tid >> 3) + rep * 32;
        int l = l0 + ll;
        size_t base = (size_t)(l * 16 + n) * 1536 + h * 64 + d8;
        u16x8 q = *(const u16x8*)(qkv + base);
        u16x8 k = *(const u16x8*)(qkv + base + 512);
        u16x8 v = *(const u16x8*)(qkv + base + 1024);
        u16x8 qu, qv;
#pragma unroll
        for (int e = 0; e < 8; e++) {
            float qf = bf2f(q[e]);
            qu[e] = f2bf(qf + bub[e]);
            qv[e] = f2bf(qf + bvb[e]);
        }
        size_t o = ((size_t)nh * 512 + l) * 64 + d8;
        *(u16x8*)(QU + o) = qu;
        *(u16x8*)(QV + o) = qv;
        *(u16x8*)(Kb + o) = k;
        *(u16x8*)(sV + ll * 72 + d8) = v;
    }
    __syncthreads();
    int d = tid >> 2, ls = (tid & 3) << 4;
    u16 tmp[16];
#pragma unroll
    for (int e = 0; e < 16; e++) tmp[e] = sV[(ls + e) * 72 + d];
    u16* dst = VT + ((size_t)nh * 64 + d) * 512 + l0 + ls;
    *(u16x8*)(dst) = *(const u16x8*)(tmp);
    *(u16x8*)(dst + 8) = *(const u16x8*)(tmp + 8);
}

// ---------- depthwise conv: sliding window, 16 outputs per thread ----------
__global__ __launch_bounds__(256) void dwconv_k(
    const u16* __restrict__ g, const float* __restrict__ w, const float* __restrict__ wb,
    const float* __restrict__ bng, const float* __restrict__ bnb, const float* __restrict__ bnm,
    const float* __restrict__ bnv, u16* __restrict__ out) {
    int idx = blockIdx.x * 256 + threadIdx.x;  // 262144 threads
    int c = idx & 511;
    int t = idx >> 9;
    int n = t & 15, l0 = (t >> 4) << 4;
    float win[46];
#pragma unroll
    for (int q = 0; q < 46; q++) {
        int ll = l0 - 15 + q;
        win[q] = (ll >= 0 && ll < 512) ? bf2f(g[((size_t)(ll * 16 + n) << 9) + c]) : 0.f;
    }
    float wgt[31];
#pragma unroll
    for (int k = 0; k < 31; k++) wgt[k] = w[c * 31 + k];
    float ivg = rsqrtf(bnv[c] + 1e-5f) * bng[c];
    float mc = bnm[c], bc = bnb[c], wbc = wb[c];
#pragma unroll
    for (int r = 0; r < 16; r++) {
        float acc = 0.f;
#pragma unroll
        for (int k = 0; k < 31; k++) acc += wgt[k] * win[r + k];
        acc += wbc;
        float y = (acc - mc) * ivg + bc;
        y = y * sigm(y);
        out[((size_t)((l0 + r) * 16 + n) << 9) + c] = f2bf(y);
    }
}

// ---------- launch ----------
extern "C" void kernel_launch(void* const* d_in, const int* in_sizes, int n_in,
                              void* d_out, int out_size, void* d_ws, size_t ws_size,
                              hipStream_t stream) {
    const float* src      = (const float*)d_in[0];
    const float* pos_emb  = (const float*)d_in[1];
    const float* ffm_w1   = (const float*)d_in[2];
    const float* ffm_b1   = (const float*)d_in[3];
    const float* ffm_w2   = (const float*)d_in[4];
    const float* ffm_b2   = (const float*)d_in[5];
    const float* ff_w1    = (const float*)d_in[6];
    const float* ff_b1    = (const float*)d_in[7];
    const float* ff_w2    = (const float*)d_in[8];
    const float* ff_b2    = (const float*)d_in[9];
    const float* in_w     = (const float*)d_in[10];
    const float* in_b     = (const float*)d_in[11];
    const float* out_w    = (const float*)d_in[12];
    const float* out_b    = (const float*)d_in[13];
    const float* pos_w    = (const float*)d_in[14];
    const float* bu       = (const float*)d_in[15];
    const float* bv       = (const float*)d_in[16];
    const float* pw1_w    = (const float*)d_in[17];
    const float* pw1_b    = (const float*)d_in[18];
    const float* dw_w     = (const float*)d_in[19];
    const float* dw_b     = (const float*)d_in[20];
    const float* bng      = (const float*)d_in[21];
    const float* bnb      = (const float*)d_in[22];
    const float* bnm      = (const float*)d_in[23];
    const float* bnv      = (const float*)d_in[24];
    const float* pw2_w    = (const float*)d_in[25];
    const float* pw2_b    = (const float*)d_in[26];
    const float* ln_ffm_g = (const float*)d_in[27];
    const float* ln_ffm_b = (const float*)d_in[28];
    const float* ln_mha_g = (const float*)d_in[29];
    const float* ln_mha_b = (const float*)d_in[30];
    const float* ln_cv_g  = (const float*)d_in[31];
    const float* ln_cv_b  = (const float*)d_in[32];
    const float* ln_ff_g  = (const float*)d_in[33];
    const float* ln_ff_b  = (const float*)d_in[34];
    const float* ln_fin_g = (const float*)d_in[35];
    const float* ln_fin_b = (const float*)d_in[36];
    (void)in_sizes; (void)n_in; (void)out_size; (void)ws_size;

    // ---- workspace layout in u16 units; total ~117 MiB ----
    const size_t MEG = 1048576;
    u16* U = (u16*)d_ws;
    float* xA = (float*)U;                // 8M u16; Pbf aliases during attention
    u16* Pbf = U;                         // 524288 u16 (8 x 1024 x 64)
    float* xB = (float*)(U + 8 * MEG);    // 8M
    u16* LNB = U + 16 * MEG;              // 4M
    u16* BIG = U + 20 * MEG;              // 16M: h1 / qkv
    u16* QU = U + 36 * MEG;               // 4M
    u16* QV = U + 40 * MEG;               // 4M
    u16* Kb = U + 44 * MEG;               // 4M
    u16* VT = U + 48 * MEG;               // 4M
    u16* WB = U + 52 * MEG;               // 6,815,232 weights bf16
    u16* w_ffm1 = WB;
    u16* w_ffm2 = WB + 1 * MEG;
    u16* w_ff1  = WB + 2 * MEG;
    u16* w_ff2  = WB + 3 * MEG;
    u16* w_in   = WB + 4 * MEG;
    u16* w_out  = WB + 4 * MEG + 786432;
    u16* w_pw1  = WB + 5 * MEG;
    u16* w_pw2  = WB + 5 * MEG + 524288;
    u16* w_pos  = WB + 6029312;           // 512x512
    u16* w_pe   = WB + 6291456;           // 1023x512
    u16* CTX = LNB;
    u16* GLU = QU;
    u16* CACT = QV;

    // ---- fused: cast all weights + ln_ffm (one dispatch) ----
    fusedpre_k<<<8704, 256, 0, stream>>>(ffm_w1, ffm_w2, ff_w1, ff_w2, in_w, out_w,
                                         pw1_w, pw2_w, pos_w, pos_emb, WB,
                                         src, ln_ffm_g, ln_ffm_b, LNB);

    // ---- FFN macaron: xB = src + 0.5*ffn(ln(src)) ----
    mgemm64_k<<<dim3(128, 32), 256, 0, stream>>>(LNB, w_ffm1, ffm_b1, nullptr, BIG,
                                                 8192, 2048, 512, 0.f, 1, 1);
    mgemm64_k<<<dim3(128, 8), 256, 0, stream>>>(BIG, w_ffm2, ffm_b2, src, xB,
                                                8192, 512, 2048, 0.5f, 0, 0);

    // ---- attention: xA = xB + attn(ln(xB)) ----
    ln512_k<true><<<2048, 256, 0, stream>>>(xB, ln_mha_g, ln_mha_b, LNB);
    qkvpos_k<<<dim3(128, 25), 256, 0, stream>>>(LNB, w_in, in_b, BIG,
                                                w_pe, w_pos, Pbf);
    repack_k<<<dim3(128, 8), 256, 0, stream>>>(BIG, bu, bv, QU, QV, Kb, VT);
    fattn_k<<<dim3(128, 16), 256, 0, stream>>>(QU, QV, Kb, Pbf, VT, CTX);
    mgemm64_k<<<dim3(128, 8), 256, 0, stream>>>(CTX, w_out, out_b, xB, xA,
                                                8192, 512, 512, 1.f, 0, 0);

    // ---- conv module: xB = xA + conv(ln(xA)) ----
    ln512_k<true><<<2048, 256, 0, stream>>>(xA, ln_cv_g, ln_cv_b, LNB);
    mgemmglu_k<<<dim3(128, 8), 256, 0, stream>>>(LNB, w_pw1, pw1_b, GLU, 512);
    dwconv_k<<<1024, 256, 0, stream>>>(GLU, dw_w, dw_b, bng, bnb, bnm, bnv, CACT);
    mgemm64_k<<<dim3(128, 8), 256, 0, stream>>>(CACT, w_pw2, pw2_b, xA, xB,
                                                8192, 512, 512, 1.f, 0, 0);

    // ---- FFN 2: xA = xB + 0.5*ffn(ln(xB)) ----
    ln512_k<true><<<2048, 256, 0, stream>>>(xB, ln_ff_g, ln_ff_b, LNB);
    mgemm64_k<<<dim3(128, 32), 256, 0, stream>>>(LNB, w_ff1, ff_b1, nullptr, BIG,
                                                 8192, 2048, 512, 0.f, 1, 1);
    mgemm64_k<<<dim3(128, 8), 256, 0, stream>>>(BIG, w_ff2, ff_b2, xB, xA,
                                                8192, 512, 2048, 0.5f, 0, 0);

    // ---- final LN -> fp32 out ----
    ln512_k<false><<<2048, 256, 0, stream>>>(xA, ln_fin_g, ln_fin_b, (float*)d_out);
}